// Round 7
// baseline (1286.839 us; speedup 1.0000x reference)
//
#include <hip/hip_runtime.h>
#include <cmath>

#define NPTS  200000
#define KNBR  16
#define MROWS 3200000   // NPTS*KNBR
#define EPSB  1e-5f
#define H2LD  260       // h2t row stride in floats (pad 256->260: 16B-aligned, kills 4-way conflicts)

__device__ __forceinline__ float gelu_f(float x) {
    return 0.5f * x * (1.0f + erff(x * 0.70710678118654752f));
}

// ---------------- pack p (12B) + f (16B) into one 32B record per point ----------------
// pk[2n]   = {p.x, p.y, p.z, 0}
// pk[2n+1] = {f.x, f.y, f.z, f.w}
// One cache line per neighbor gather instead of 2-3.
__global__ __launch_bounds__(256) void k_pack(
    const float* __restrict__ p, const float4* __restrict__ f,
    float4* __restrict__ pk)
{
    int n = blockIdx.x * 256 + threadIdx.x;
    if (n < NPTS) {
        float4 a;
        a.x = p[n * 3 + 0]; a.y = p[n * 3 + 1]; a.z = p[n * 3 + 2]; a.w = 0.f;
        pk[2 * n]     = a;
        pk[2 * n + 1] = f[n];
    }
}

// ---------------- stats over x itself: sum x (7) + sum x x^T (28) ----------------
// y1 = x @ w1 is linear, so BN1 mean/var follow from these 35 moments.
__global__ __launch_bounds__(256) void k_stats1(
    const float4* __restrict__ pk, const int* __restrict__ gidx,
    float* __restrict__ stats)
{
    __shared__ float red[4 * 35];

    float acc[35];
#pragma unroll
    for (int c = 0; c < 35; c++) acc[c] = 0.f;

    int stride = gridDim.x * 256;
    for (int r = blockIdx.x * 256 + threadIdx.x; r < MROWS; r += stride) {
        int n = r >> 4;
        int idx = gidx[r];
        float4 pa = pk[2 * idx];
        float4 fb = pk[2 * idx + 1];
        float4 pc = pk[2 * n];        // wave-broadcast within 16-lane group
        float x[7];
        x[0] = pa.x - pc.x; x[1] = pa.y - pc.y; x[2] = pa.z - pc.z;
        x[3] = fb.x; x[4] = fb.y; x[5] = fb.z; x[6] = fb.w;
#pragma unroll
        for (int i = 0; i < 7; i++) acc[i] += x[i];
        int t = 7;
#pragma unroll
        for (int i = 0; i < 7; i++)
#pragma unroll
            for (int l = i; l < 7; l++) { acc[t] = fmaf(x[i], x[l], acc[t]); t++; }
    }
    int lane = threadIdx.x & 63, wv = threadIdx.x >> 6;
#pragma unroll
    for (int c = 0; c < 35; c++) {
        float v = acc[c];
        v += __shfl_down(v, 32); v += __shfl_down(v, 16); v += __shfl_down(v, 8);
        v += __shfl_down(v, 4);  v += __shfl_down(v, 2);  v += __shfl_down(v, 1);
        if (lane == 0) red[wv * 35 + c] = v;
    }
    __syncthreads();
    for (int c = threadIdx.x; c < 35; c += 256)
        atomicAdd(&stats[c], red[c] + red[35 + c] + red[70 + c] + red[105 + c]);
}

// BN1 finalize from x-moments: mean_j = w_j . mx ; E[y^2]_j = w_j^T Mxx w_j
__global__ void k_fin1(const float* __restrict__ stats, const float* __restrict__ w1,
                       const float* __restrict__ g, const float* __restrict__ b,
                       float* __restrict__ scsh)
{
    int j = threadIdx.x;
    if (j < 16) {
        const float invM = 1.0f / (float)MROWS;
        float w[7];
#pragma unroll
        for (int i = 0; i < 7; i++) w[i] = w1[i * 16 + j];
        float m = 0.f;
#pragma unroll
        for (int i = 0; i < 7; i++) m = fmaf(w[i], stats[i], m);
        m *= invM;
        float e2 = 0.f;
        int t = 7;
#pragma unroll
        for (int i = 0; i < 7; i++)
#pragma unroll
            for (int l = i; l < 7; l++) {
                float coeff = (i == l) ? 1.0f : 2.0f;
                e2 = fmaf(coeff * w[i] * w[l], stats[t], e2);
                t++;
            }
        e2 *= invM;
        float v = e2 - m * m;
        float sc = g[j] * rsqrtf(v + EPSB);
        scsh[j] = sc;
        scsh[16 + j] = fmaf(-m, sc, b[j]);
    }
}

// ---------------- h1 moments, pass A: pairs (i,l), 0<=i<6, i<=l<16 -> 81 ----------------
// y2 = h1 @ w2 is linear in h1, so BN2 stats follow from h1 moments (no 64-acc spill).
// 81 accumulators (vs 100) -> lower VGPR -> more waves to hide gather latency.
__global__ __launch_bounds__(256) void k_stats2a(
    const float4* __restrict__ pk, const int* __restrict__ gidx,
    const float* __restrict__ w1, const float* __restrict__ scsh1,
    float* __restrict__ stats)
{
    __shared__ __align__(16) float w1s[112];
    __shared__ float sc1s[16], sh1s[16];
    __shared__ float red[4 * 81];
    for (int i = threadIdx.x; i < 112; i += 256) w1s[i] = w1[i];
    if (threadIdx.x < 16) {
        sc1s[threadIdx.x] = scsh1[threadIdx.x];
        sh1s[threadIdx.x] = scsh1[16 + threadIdx.x];
    }
    __syncthreads();
    const float4* w1v = (const float4*)w1s;   // [7][4]

    float acc[81];
#pragma unroll
    for (int c = 0; c < 81; c++) acc[c] = 0.f;

    int stride = gridDim.x * 256;
    for (int r = blockIdx.x * 256 + threadIdx.x; r < MROWS; r += stride) {
        int n = r >> 4;
        int idx = gidx[r];
        float4 pa = pk[2 * idx];
        float4 fb = pk[2 * idx + 1];
        float4 pc = pk[2 * n];
        float x[7];
        x[0] = pa.x - pc.x; x[1] = pa.y - pc.y; x[2] = pa.z - pc.z;
        x[3] = fb.x; x[4] = fb.y; x[5] = fb.z; x[6] = fb.w;
        float h1[16];
#pragma unroll
        for (int j0 = 0; j0 < 16; j0 += 4) {
            float y0 = 0.f, y1 = 0.f, y2 = 0.f, y3 = 0.f;
#pragma unroll
            for (int i = 0; i < 7; i++) {
                float4 w = w1v[i * 4 + (j0 >> 2)];
                float xi = x[i];
                y0 = fmaf(xi, w.x, y0); y1 = fmaf(xi, w.y, y1);
                y2 = fmaf(xi, w.z, y2); y3 = fmaf(xi, w.w, y3);
            }
            h1[j0 + 0] = gelu_f(fmaf(y0, sc1s[j0 + 0], sh1s[j0 + 0]));
            h1[j0 + 1] = gelu_f(fmaf(y1, sc1s[j0 + 1], sh1s[j0 + 1]));
            h1[j0 + 2] = gelu_f(fmaf(y2, sc1s[j0 + 2], sh1s[j0 + 2]));
            h1[j0 + 3] = gelu_f(fmaf(y3, sc1s[j0 + 3], sh1s[j0 + 3]));
        }
        int t = 0;
#pragma unroll
        for (int i = 0; i < 6; i++)
#pragma unroll
            for (int l = i; l < 16; l++) { acc[t] = fmaf(h1[i], h1[l], acc[t]); t++; }
    }
    int lane = threadIdx.x & 63, wv = threadIdx.x >> 6;
#pragma unroll
    for (int c = 0; c < 81; c++) {
        float v = acc[c];
        v += __shfl_down(v, 32); v += __shfl_down(v, 16); v += __shfl_down(v, 8);
        v += __shfl_down(v, 4);  v += __shfl_down(v, 2);  v += __shfl_down(v, 1);
        if (lane == 0) red[wv * 81 + c] = v;
    }
    __syncthreads();
    for (int c = threadIdx.x; c < 81; c += 256)
        atomicAdd(&stats[c], red[c] + red[81 + c] + red[162 + c] + red[243 + c]);
}

// ---------------- h1 moments, pass B: sums (16) + pairs (i,l), 6<=i<=l<16 (55) ----------------
__global__ __launch_bounds__(256) void k_stats2b(
    const float4* __restrict__ pk, const int* __restrict__ gidx,
    const float* __restrict__ w1, const float* __restrict__ scsh1,
    float* __restrict__ stats)
{
    __shared__ __align__(16) float w1s[112];
    __shared__ float sc1s[16], sh1s[16];
    __shared__ float red[4 * 71];
    for (int i = threadIdx.x; i < 112; i += 256) w1s[i] = w1[i];
    if (threadIdx.x < 16) {
        sc1s[threadIdx.x] = scsh1[threadIdx.x];
        sh1s[threadIdx.x] = scsh1[16 + threadIdx.x];
    }
    __syncthreads();
    const float4* w1v = (const float4*)w1s;   // [7][4]

    float acc[71];
#pragma unroll
    for (int c = 0; c < 71; c++) acc[c] = 0.f;

    int stride = gridDim.x * 256;
    for (int r = blockIdx.x * 256 + threadIdx.x; r < MROWS; r += stride) {
        int n = r >> 4;
        int idx = gidx[r];
        float4 pa = pk[2 * idx];
        float4 fb = pk[2 * idx + 1];
        float4 pc = pk[2 * n];
        float x[7];
        x[0] = pa.x - pc.x; x[1] = pa.y - pc.y; x[2] = pa.z - pc.z;
        x[3] = fb.x; x[4] = fb.y; x[5] = fb.z; x[6] = fb.w;
        float h1[16];
#pragma unroll
        for (int j0 = 0; j0 < 16; j0 += 4) {
            float y0 = 0.f, y1 = 0.f, y2 = 0.f, y3 = 0.f;
#pragma unroll
            for (int i = 0; i < 7; i++) {
                float4 w = w1v[i * 4 + (j0 >> 2)];
                float xi = x[i];
                y0 = fmaf(xi, w.x, y0); y1 = fmaf(xi, w.y, y1);
                y2 = fmaf(xi, w.z, y2); y3 = fmaf(xi, w.w, y3);
            }
            h1[j0 + 0] = gelu_f(fmaf(y0, sc1s[j0 + 0], sh1s[j0 + 0]));
            h1[j0 + 1] = gelu_f(fmaf(y1, sc1s[j0 + 1], sh1s[j0 + 1]));
            h1[j0 + 2] = gelu_f(fmaf(y2, sc1s[j0 + 2], sh1s[j0 + 2]));
            h1[j0 + 3] = gelu_f(fmaf(y3, sc1s[j0 + 3], sh1s[j0 + 3]));
        }
#pragma unroll
        for (int i = 0; i < 16; i++) acc[i] += h1[i];
        int t = 16;
#pragma unroll
        for (int i = 6; i < 16; i++)
#pragma unroll
            for (int l = i; l < 16; l++) { acc[t] = fmaf(h1[i], h1[l], acc[t]); t++; }
    }
    int lane = threadIdx.x & 63, wv = threadIdx.x >> 6;
#pragma unroll
    for (int c = 0; c < 71; c++) {
        float v = acc[c];
        v += __shfl_down(v, 32); v += __shfl_down(v, 16); v += __shfl_down(v, 8);
        v += __shfl_down(v, 4);  v += __shfl_down(v, 2);  v += __shfl_down(v, 1);
        if (lane == 0) red[wv * 71 + c] = v;
    }
    __syncthreads();
    for (int c = threadIdx.x; c < 71; c += 256)
        atomicAdd(&stats[81 + c], red[c] + red[71 + c] + red[142 + c] + red[213 + c]);
}

// BN2 finalize from h1 moments. stats layout: [0..80] pairs i<6, [81..96] sums,
// [97..151] pairs i>=6. mean_j = w2_j . S1 / M ; E[y^2]_j = w2_j^T M2 w2_j / M.
__global__ void k_fin2(const float* __restrict__ stats, const float* __restrict__ w2,
                       const float* __restrict__ g, const float* __restrict__ b,
                       float* __restrict__ scsh)
{
    int j = threadIdx.x;
    if (j < 32) {
        const float invM = 1.0f / (float)MROWS;
        float w[16];
#pragma unroll
        for (int i = 0; i < 16; i++) w[i] = w2[i * 32 + j];
        float m = 0.f;
#pragma unroll
        for (int i = 0; i < 16; i++) m = fmaf(w[i], stats[81 + i], m);
        m *= invM;
        float e2 = 0.f;
        int t = 0;
#pragma unroll
        for (int i = 0; i < 6; i++)
#pragma unroll
            for (int l = i; l < 16; l++) {
                float coeff = (i == l) ? 1.0f : 2.0f;
                e2 = fmaf(coeff * w[i] * w[l], stats[t], e2);
                t++;
            }
        t = 97;
#pragma unroll
        for (int i = 6; i < 16; i++)
#pragma unroll
            for (int l = i; l < 16; l++) {
                float coeff = (i == l) ? 1.0f : 2.0f;
                e2 = fmaf(coeff * w[i] * w[l], stats[t], e2);
                t++;
            }
        e2 *= invM;
        float v = e2 - m * m;
        float sc = g[j] * rsqrtf(v + EPSB);
        scsh[j] = sc;
        scsh[32 + j] = fmaf(-m, sc, b[j]);
    }
}

// ---------------- two-phase pool kernel ----------------
// Phase A (thread = row): compute h2[32], store TRANSPOSED to LDS h2t[32][H2LD].
// Phase B (thread = (pt = tid>>4, cc = tid&15)): layer3 for 4 channels of one
// point, maxing over its 16 neighbors read from h2t as float4 quads.
// No shuffles; DS ops/row ~halved; pooled writes coalesced.
// Grid: 3125 blocks * 256 thr * 4 iters == 3,200,000 rows exactly.
__global__ __launch_bounds__(256) void k_pool2(
    const float* __restrict__ p, const float4* __restrict__ f,
    const int* __restrict__ gidx,
    const float* __restrict__ w1, const float* __restrict__ w2,
    const float* __restrict__ w3,
    const float* __restrict__ scsh1, const float* __restrict__ scsh2,
    float* __restrict__ stats, float* __restrict__ pooled)
{
    __shared__ __align__(16) float w1s[112];
    __shared__ __align__(16) float w2s[512];
    __shared__ __align__(16) float w3s[2048];
    __shared__ __align__(16) float h2t[32 * H2LD];
    __shared__ float sc1s[16], sh1s[16], sc2s[32], sh2s[32];
    __shared__ float reds[256];
    __shared__ float redq[256];
    int tid = threadIdx.x;
    for (int i = tid; i < 112; i += 256) w1s[i] = w1[i];
    for (int i = tid; i < 512; i += 256) w2s[i] = w2[i];
    for (int i = tid; i < 2048; i += 256) w3s[i] = w3[i];
    if (tid < 16) { sc1s[tid] = scsh1[tid]; sh1s[tid] = scsh1[16 + tid]; }
    if (tid < 32) { sc2s[tid] = scsh2[tid]; sh2s[tid] = scsh2[32 + tid]; }
    __syncthreads();

    const float4* w1v = (const float4*)w1s;   // [7][4]
    const float4* w2v = (const float4*)w2s;   // [16][8]
    const float4* w3v = (const float4*)w3s;   // [32][16]

    int lane = tid & 63;
    int pt = tid >> 4;      // phase-B point (0..15)
    int cc = tid & 15;      // phase-B channel chunk: channels [4cc, 4cc+3]

    float s0 = 0.f, s1 = 0.f, s2 = 0.f, s3 = 0.f;
    float q0 = 0.f, q1 = 0.f, q2 = 0.f, q3 = 0.f;

#pragma unroll 1
    for (int it = 0; it < 4; it++) {
        // ---------- phase A: one row per thread ----------
        int r = it * 800000 + blockIdx.x * 256 + tid;
        int n = r >> 4;
        int idx = gidx[r];
        float4 fv = f[idx];
        float x[7];
        x[0] = p[idx * 3 + 0] - p[n * 3 + 0];
        x[1] = p[idx * 3 + 1] - p[n * 3 + 1];
        x[2] = p[idx * 3 + 2] - p[n * 3 + 2];
        x[3] = fv.x; x[4] = fv.y; x[5] = fv.z; x[6] = fv.w;

        float h1[16];
#pragma unroll
        for (int j0 = 0; j0 < 16; j0 += 4) {
            float y0 = 0.f, y1 = 0.f, y2 = 0.f, y3 = 0.f;
#pragma unroll
            for (int i = 0; i < 7; i++) {
                float4 w = w1v[i * 4 + (j0 >> 2)];
                float xi = x[i];
                y0 = fmaf(xi, w.x, y0); y1 = fmaf(xi, w.y, y1);
                y2 = fmaf(xi, w.z, y2); y3 = fmaf(xi, w.w, y3);
            }
            h1[j0 + 0] = gelu_f(fmaf(y0, sc1s[j0 + 0], sh1s[j0 + 0]));
            h1[j0 + 1] = gelu_f(fmaf(y1, sc1s[j0 + 1], sh1s[j0 + 1]));
            h1[j0 + 2] = gelu_f(fmaf(y2, sc1s[j0 + 2], sh1s[j0 + 2]));
            h1[j0 + 3] = gelu_f(fmaf(y3, sc1s[j0 + 3], sh1s[j0 + 3]));
        }
#pragma unroll
        for (int j0 = 0; j0 < 32; j0 += 4) {
            float y0 = 0.f, y1 = 0.f, y2 = 0.f, y3 = 0.f;
#pragma unroll
            for (int i = 0; i < 16; i++) {
                float4 w = w2v[i * 8 + (j0 >> 2)];
                float hi = h1[i];
                y0 = fmaf(hi, w.x, y0); y1 = fmaf(hi, w.y, y1);
                y2 = fmaf(hi, w.z, y2); y3 = fmaf(hi, w.w, y3);
            }
            // transposed store: h2t[channel][local_row]; lanes write consecutive
            // addresses -> conflict-free
            h2t[(j0 + 0) * H2LD + tid] = gelu_f(fmaf(y0, sc2s[j0 + 0], sh2s[j0 + 0]));
            h2t[(j0 + 1) * H2LD + tid] = gelu_f(fmaf(y1, sc2s[j0 + 1], sh2s[j0 + 1]));
            h2t[(j0 + 2) * H2LD + tid] = gelu_f(fmaf(y2, sc2s[j0 + 2], sh2s[j0 + 2]));
            h2t[(j0 + 3) * H2LD + tid] = gelu_f(fmaf(y3, sc2s[j0 + 3], sh2s[j0 + 3]));
        }
        __syncthreads();

        // ---------- phase B: (point, channel-chunk) per thread ----------
        float m0 = -3.0e38f, m1 = -3.0e38f, m2 = -3.0e38f, m3 = -3.0e38f;
#pragma unroll 1
        for (int qd = 0; qd < 4; qd++) {          // 4 neighbors at a time
            int rb = (pt << 4) + (qd << 2);       // local row base
            float a00 = 0.f, a01 = 0.f, a02 = 0.f, a03 = 0.f;
            float a10 = 0.f, a11 = 0.f, a12 = 0.f, a13 = 0.f;
            float a20 = 0.f, a21 = 0.f, a22 = 0.f, a23 = 0.f;
            float a30 = 0.f, a31 = 0.f, a32 = 0.f, a33 = 0.f;
#pragma unroll 8
            for (int i = 0; i < 32; i++) {
                float4 hv = *(const float4*)&h2t[i * H2LD + rb];   // 4 nbrs, ch i
                float4 wf = w3v[i * 16 + cc];                       // 4 out-ch
                a00 = fmaf(hv.x, wf.x, a00); a01 = fmaf(hv.x, wf.y, a01);
                a02 = fmaf(hv.x, wf.z, a02); a03 = fmaf(hv.x, wf.w, a03);
                a10 = fmaf(hv.y, wf.x, a10); a11 = fmaf(hv.y, wf.y, a11);
                a12 = fmaf(hv.y, wf.z, a12); a13 = fmaf(hv.y, wf.w, a13);
                a20 = fmaf(hv.z, wf.x, a20); a21 = fmaf(hv.z, wf.y, a21);
                a22 = fmaf(hv.z, wf.z, a22); a23 = fmaf(hv.z, wf.w, a23);
                a30 = fmaf(hv.w, wf.x, a30); a31 = fmaf(hv.w, wf.y, a31);
                a32 = fmaf(hv.w, wf.z, a32); a33 = fmaf(hv.w, wf.w, a33);
            }
            m0 = fmaxf(fmaxf(fmaxf(m0, a00), fmaxf(a10, a20)), a30);
            m1 = fmaxf(fmaxf(fmaxf(m1, a01), fmaxf(a11, a21)), a31);
            m2 = fmaxf(fmaxf(fmaxf(m2, a02), fmaxf(a12, a22)), a32);
            m3 = fmaxf(fmaxf(fmaxf(m3, a03), fmaxf(a13, a23)), a33);
        }
        int np = it * 50000 + blockIdx.x * 16 + pt;
        *(float4*)&pooled[(size_t)np * 64 + cc * 4] = make_float4(m0, m1, m2, m3);
        s0 += m0; q0 = fmaf(m0, m0, q0);
        s1 += m1; q1 = fmaf(m1, m1, q1);
        s2 += m2; q2 = fmaf(m2, m2, q2);
        s3 += m3; q3 = fmaf(m3, m3, q3);
        __syncthreads();   // protect h2t before next iteration's writes
    }

    // stats fold: lanes cc, cc+16, cc+32, cc+48 hold different points, same channels
    s0 += __shfl_down(s0, 32); s0 += __shfl_down(s0, 16);
    s1 += __shfl_down(s1, 32); s1 += __shfl_down(s1, 16);
    s2 += __shfl_down(s2, 32); s2 += __shfl_down(s2, 16);
    s3 += __shfl_down(s3, 32); s3 += __shfl_down(s3, 16);
    q0 += __shfl_down(q0, 32); q0 += __shfl_down(q0, 16);
    q1 += __shfl_down(q1, 32); q1 += __shfl_down(q1, 16);
    q2 += __shfl_down(q2, 32); q2 += __shfl_down(q2, 16);
    q3 += __shfl_down(q3, 32); q3 += __shfl_down(q3, 16);
    int wv = tid >> 6;
    if (lane < 16) {
        reds[wv * 64 + lane * 4 + 0] = s0;
        reds[wv * 64 + lane * 4 + 1] = s1;
        reds[wv * 64 + lane * 4 + 2] = s2;
        reds[wv * 64 + lane * 4 + 3] = s3;
        redq[wv * 64 + lane * 4 + 0] = q0;
        redq[wv * 64 + lane * 4 + 1] = q1;
        redq[wv * 64 + lane * 4 + 2] = q2;
        redq[wv * 64 + lane * 4 + 3] = q3;
    }
    __syncthreads();
    if (tid < 64) {
        atomicAdd(&stats[tid],
                  reds[tid] + reds[64 + tid] + reds[128 + tid] + reds[192 + tid]);
        atomicAdd(&stats[64 + tid],
                  redq[tid] + redq[64 + tid] + redq[128 + tid] + redq[192 + tid]);
    }
}

// double-BN collapse: z = a1*(y-m)+b_nbr has mean b_nbr, var a1^2*v exactly
__global__ void k_fin3(const float* __restrict__ stats,
                       const float* __restrict__ g_nbr, const float* __restrict__ g_post,
                       const float* __restrict__ b_post, float* __restrict__ scsh)
{
    int j = threadIdx.x;
    if (j < 64) {
        float m = stats[j] * (1.0f / NPTS);
        float v = stats[64 + j] * (1.0f / NPTS) - m * m;
        float a1 = g_nbr[j] * rsqrtf(v + EPSB);
        float s3 = g_post[j] * a1 * rsqrtf(fmaf(a1 * a1, v, EPSB));
        scsh[j] = s3;
        scsh[64 + j] = fmaf(-m, s3, b_post[j]);
    }
}

// ---------------- head: (N x 64) @ (64 x 256) ----------------
__global__ __launch_bounds__(256) void k_head(
    const float* __restrict__ pooled, const float* __restrict__ scsh3,
    const float* __restrict__ wpost, float* __restrict__ out)
{
    __shared__ float rowbuf[512];
    __shared__ float s3s[64], c3s[64];
    int tid = threadIdx.x;
    if (tid < 64) { s3s[tid] = scsh3[tid]; c3s[tid] = scsh3[64 + tid]; }
    float wcol[64];
#pragma unroll
    for (int j = 0; j < 64; j++) wcol[j] = wpost[j * 256 + tid];
    __syncthreads();

    const int nchunks = NPTS / 8;  // 25000
    for (int c = blockIdx.x; c < nchunks; c += gridDim.x) {
        int n0 = c * 8;
#pragma unroll
        for (int t = tid; t < 512; t += 256) {
            int rr = t >> 6, j = t & 63;
            rowbuf[t] = fmaf(pooled[(size_t)(n0 + rr) * 64 + j], s3s[j], c3s[j]);
        }
        __syncthreads();
#pragma unroll
        for (int rr = 0; rr < 8; rr++) {
            float acc = 0.f;
#pragma unroll
            for (int j = 0; j < 64; j++) acc = fmaf(rowbuf[rr * 64 + j], wcol[j], acc);
            out[(size_t)(n0 + rr) * 256 + tid] = acc;
        }
        __syncthreads();
    }
}

extern "C" void kernel_launch(void* const* d_in, const int* in_sizes, int n_in,
                              void* d_out, int out_size, void* d_ws, size_t ws_size,
                              hipStream_t stream)
{
    const float*  p    = (const float*)d_in[0];
    const float4* f    = (const float4*)d_in[1];
    const int*    gidx = (const int*)d_in[2];
    const float*  w1   = (const float*)d_in[3];
    const float*  g1   = (const float*)d_in[4];
    const float*  b1   = (const float*)d_in[5];
    const float*  w2   = (const float*)d_in[6];
    const float*  g2   = (const float*)d_in[7];
    const float*  b2   = (const float*)d_in[8];
    const float*  w3   = (const float*)d_in[9];
    const float*  gn   = (const float*)d_in[10];
    // d_in[11] = b_nbr: cancels exactly in the collapsed double-BN
    const float*  gp   = (const float*)d_in[12];
    const float*  bp   = (const float*)d_in[13];
    const float*  wp   = (const float*)d_in[14];
    float* out = (float*)d_out;
    float* ws  = (float*)d_ws;

    float* stats1 = ws;          // 35 floats (x moments)
    float* scsh1  = ws + 40;     // 32
    float* stats2 = ws + 80;     // 152 floats (h1 moments: 81 pairs + 16 sums + 55 pairs)
    float* scsh2  = ws + 240;    // 64
    float* stats3 = ws + 304;    // 128
    float* scsh3  = ws + 432;    // 128
    float* pooled = ws + 1024;   // 12.8M floats
    // pk ALIASES pooled: pk is dead before k_pool2 writes pooled (k_pool2 does
    // not read pk), so no extra workspace is consumed.
    float4* pk    = (float4*)(ws + 1024);   // 200000 * 2 float4 = 1.6M floats

    hipMemsetAsync(d_ws, 0, 2048, stream);
    k_pack<<<(NPTS + 255) / 256, 256, 0, stream>>>(p, f, pk);
    k_stats1<<<2048, 256, 0, stream>>>(pk, gidx, stats1);
    k_fin1<<<1, 64, 0, stream>>>(stats1, w1, g1, b1, scsh1);
    k_stats2a<<<2048, 256, 0, stream>>>(pk, gidx, w1, scsh1, stats2);
    k_stats2b<<<2048, 256, 0, stream>>>(pk, gidx, w1, scsh1, stats2);
    k_fin2<<<1, 64, 0, stream>>>(stats2, w2, g2, b2, scsh2);
    k_pool2<<<3125, 256, 0, stream>>>(p, f, gidx, w1, w2, w3, scsh1, scsh2, stats3, pooled);
    k_fin3<<<1, 64, 0, stream>>>(stats3, gn, gp, bp, scsh3);
    k_head<<<1024, 256, 0, stream>>>(pooled, scsh3, wp, out);
}

// Round 8
// 1281.475 us; speedup vs baseline: 1.0042x; 1.0042x over previous
//
#include <hip/hip_runtime.h>
#include <cmath>

#define NPTS  200000
#define KNBR  16
#define MROWS 3200000   // NPTS*KNBR
#define EPSB  1e-5f
#define H2LD  260       // h2t row stride in floats (pad 256->260: 16B-aligned, kills 4-way conflicts)

__device__ __forceinline__ float gelu_f(float x) {
    return 0.5f * x * (1.0f + erff(x * 0.70710678118654752f));
}

// ---------------- pack p (12B) + f (16B) into one 32B record per point ----------------
__global__ __launch_bounds__(256) void k_pack(
    const float* __restrict__ p, const float4* __restrict__ f,
    float4* __restrict__ pk)
{
    int n = blockIdx.x * 256 + threadIdx.x;
    if (n < NPTS) {
        float4 a;
        a.x = p[n * 3 + 0]; a.y = p[n * 3 + 1]; a.z = p[n * 3 + 2]; a.w = 0.f;
        pk[2 * n]     = a;
        pk[2 * n + 1] = f[n];
    }
}

// ================= BIG-WORKSPACE PATH =================
// ONE gather pass: compute y1 = x@w1 per row, accumulate BN1 sums (32 accs ->
// ~64 VGPR -> 8 waves/SIMD, gather latency hidden), and dump y1 to global in
// 64-row-tiled column-major layout: y1d[(r>>6)*1024 + j*64 + (r&63)] so every
// store (and later load) is a fully coalesced wave access.
__global__ __launch_bounds__(256) void k_gy1(
    const float4* __restrict__ pk, const int* __restrict__ gidx,
    const float* __restrict__ w1, float* __restrict__ stats,
    float* __restrict__ y1d)
{
    __shared__ __align__(16) float w1s[112];
    __shared__ float red[4 * 32];
    for (int i = threadIdx.x; i < 112; i += 256) w1s[i] = w1[i];
    __syncthreads();
    const float4* w1v = (const float4*)w1s;   // [7][4]

    float acc[32];
#pragma unroll
    for (int c = 0; c < 32; c++) acc[c] = 0.f;

    int tid = threadIdx.x;
    int lr = tid & 63;                 // r & 63 == tid & 63 (stride, bid*256 are %64==0)
    int stride = gridDim.x * 256;
    for (int r = blockIdx.x * 256 + tid; r < MROWS; r += stride) {
        int n = r >> 4;
        int idx = gidx[r];
        float4 pa = pk[2 * idx];
        float4 fb = pk[2 * idx + 1];
        float4 pc = pk[2 * n];
        float x[7];
        x[0] = pa.x - pc.x; x[1] = pa.y - pc.y; x[2] = pa.z - pc.z;
        x[3] = fb.x; x[4] = fb.y; x[5] = fb.z; x[6] = fb.w;
        float* yb = y1d + (size_t)(r >> 6) * 1024 + lr;
#pragma unroll
        for (int j0 = 0; j0 < 16; j0 += 4) {
            float y0 = 0.f, y1 = 0.f, y2 = 0.f, y3 = 0.f;
#pragma unroll
            for (int i = 0; i < 7; i++) {
                float4 w = w1v[i * 4 + (j0 >> 2)];
                float xi = x[i];
                y0 = fmaf(xi, w.x, y0); y1 = fmaf(xi, w.y, y1);
                y2 = fmaf(xi, w.z, y2); y3 = fmaf(xi, w.w, y3);
            }
            yb[(j0 + 0) * 64] = y0; yb[(j0 + 1) * 64] = y1;
            yb[(j0 + 2) * 64] = y2; yb[(j0 + 3) * 64] = y3;
            acc[j0 + 0] += y0; acc[16 + j0 + 0] += y0 * y0;
            acc[j0 + 1] += y1; acc[16 + j0 + 1] += y1 * y1;
            acc[j0 + 2] += y2; acc[16 + j0 + 2] += y2 * y2;
            acc[j0 + 3] += y3; acc[16 + j0 + 3] += y3 * y3;
        }
    }
    int lane = tid & 63, wv = tid >> 6;
#pragma unroll
    for (int c = 0; c < 32; c++) {
        float v = acc[c];
        v += __shfl_down(v, 32); v += __shfl_down(v, 16); v += __shfl_down(v, 8);
        v += __shfl_down(v, 4);  v += __shfl_down(v, 2);  v += __shfl_down(v, 1);
        if (lane == 0) red[wv * 32 + c] = v;
    }
    __syncthreads();
    for (int c = tid; c < 32; c += 256)
        atomicAdd(&stats[c], red[c] + red[32 + c] + red[64 + c] + red[96 + c]);
}

// BN1 finalize from y1 sums
__global__ void k_fin1b(const float* __restrict__ stats, const float* __restrict__ g,
                        const float* __restrict__ b, float* __restrict__ scsh)
{
    int j = threadIdx.x;
    if (j < 16) {
        const float invM = 1.0f / (float)MROWS;
        float m = stats[j] * invM;
        float v = stats[16 + j] * invM - m * m;
        float sc = g[j] * rsqrtf(v + EPSB);
        scsh[j] = sc;
        scsh[16 + j] = fmaf(-m, sc, b[j]);
    }
}

// h1 moments pass A from the y1 dump: pairs (i,l), 0<=i<6, i<=l<16 -> 81.
// Pure streaming: coalesced loads, no gather, no layer-1 recompute.
__global__ __launch_bounds__(256) void k_momA(
    const float* __restrict__ y1d, const float* __restrict__ scsh1,
    float* __restrict__ stats)
{
    __shared__ float sc1s[16], sh1s[16];
    __shared__ float red[4 * 81];
    if (threadIdx.x < 16) {
        sc1s[threadIdx.x] = scsh1[threadIdx.x];
        sh1s[threadIdx.x] = scsh1[16 + threadIdx.x];
    }
    __syncthreads();

    float acc[81];
#pragma unroll
    for (int c = 0; c < 81; c++) acc[c] = 0.f;

    int tid = threadIdx.x;
    int lr = tid & 63;
    int stride = gridDim.x * 256;
    for (int r = blockIdx.x * 256 + tid; r < MROWS; r += stride) {
        const float* yb = y1d + (size_t)(r >> 6) * 1024 + lr;
        float h1[16];
#pragma unroll
        for (int j = 0; j < 16; j++)
            h1[j] = gelu_f(fmaf(yb[j * 64], sc1s[j], sh1s[j]));
        int t = 0;
#pragma unroll
        for (int i = 0; i < 6; i++)
#pragma unroll
            for (int l = i; l < 16; l++) { acc[t] = fmaf(h1[i], h1[l], acc[t]); t++; }
    }
    int lane = tid & 63, wv = tid >> 6;
#pragma unroll
    for (int c = 0; c < 81; c++) {
        float v = acc[c];
        v += __shfl_down(v, 32); v += __shfl_down(v, 16); v += __shfl_down(v, 8);
        v += __shfl_down(v, 4);  v += __shfl_down(v, 2);  v += __shfl_down(v, 1);
        if (lane == 0) red[wv * 81 + c] = v;
    }
    __syncthreads();
    for (int c = tid; c < 81; c += 256)
        atomicAdd(&stats[c], red[c] + red[81 + c] + red[162 + c] + red[243 + c]);
}

// h1 moments pass B from the y1 dump: sums (16) + pairs 6<=i<=l<16 (55)
__global__ __launch_bounds__(256) void k_momB(
    const float* __restrict__ y1d, const float* __restrict__ scsh1,
    float* __restrict__ stats)
{
    __shared__ float sc1s[16], sh1s[16];
    __shared__ float red[4 * 71];
    if (threadIdx.x < 16) {
        sc1s[threadIdx.x] = scsh1[threadIdx.x];
        sh1s[threadIdx.x] = scsh1[16 + threadIdx.x];
    }
    __syncthreads();

    float acc[71];
#pragma unroll
    for (int c = 0; c < 71; c++) acc[c] = 0.f;

    int tid = threadIdx.x;
    int lr = tid & 63;
    int stride = gridDim.x * 256;
    for (int r = blockIdx.x * 256 + tid; r < MROWS; r += stride) {
        const float* yb = y1d + (size_t)(r >> 6) * 1024 + lr;
        float h1[16];
#pragma unroll
        for (int j = 0; j < 16; j++)
            h1[j] = gelu_f(fmaf(yb[j * 64], sc1s[j], sh1s[j]));
#pragma unroll
        for (int i = 0; i < 16; i++) acc[i] += h1[i];
        int t = 16;
#pragma unroll
        for (int i = 6; i < 16; i++)
#pragma unroll
            for (int l = i; l < 16; l++) { acc[t] = fmaf(h1[i], h1[l], acc[t]); t++; }
    }
    int lane = tid & 63, wv = tid >> 6;
#pragma unroll
    for (int c = 0; c < 71; c++) {
        float v = acc[c];
        v += __shfl_down(v, 32); v += __shfl_down(v, 16); v += __shfl_down(v, 8);
        v += __shfl_down(v, 4);  v += __shfl_down(v, 2);  v += __shfl_down(v, 1);
        if (lane == 0) red[wv * 71 + c] = v;
    }
    __syncthreads();
    for (int c = tid; c < 71; c += 256)
        atomicAdd(&stats[81 + c], red[c] + red[71 + c] + red[142 + c] + red[213 + c]);
}

// BN2 finalize from h1 moments: [0..80] pairs i<6, [81..96] sums, [97..151] pairs i>=6
__global__ void k_fin2(const float* __restrict__ stats, const float* __restrict__ w2,
                       const float* __restrict__ g, const float* __restrict__ b,
                       float* __restrict__ scsh)
{
    int j = threadIdx.x;
    if (j < 32) {
        const float invM = 1.0f / (float)MROWS;
        float w[16];
#pragma unroll
        for (int i = 0; i < 16; i++) w[i] = w2[i * 32 + j];
        float m = 0.f;
#pragma unroll
        for (int i = 0; i < 16; i++) m = fmaf(w[i], stats[81 + i], m);
        m *= invM;
        float e2 = 0.f;
        int t = 0;
#pragma unroll
        for (int i = 0; i < 6; i++)
#pragma unroll
            for (int l = i; l < 16; l++) {
                float coeff = (i == l) ? 1.0f : 2.0f;
                e2 = fmaf(coeff * w[i] * w[l], stats[t], e2);
                t++;
            }
        t = 97;
#pragma unroll
        for (int i = 6; i < 16; i++)
#pragma unroll
            for (int l = i; l < 16; l++) {
                float coeff = (i == l) ? 1.0f : 2.0f;
                e2 = fmaf(coeff * w[i] * w[l], stats[t], e2);
                t++;
            }
        e2 *= invM;
        float v = e2 - m * m;
        float sc = g[j] * rsqrtf(v + EPSB);
        scsh[j] = sc;
        scsh[32 + j] = fmaf(-m, sc, b[j]);
    }
}

// Two-phase pool kernel, y1-dump variant: phase A reads y1 coalesced (no
// gather, no layer-1), applies BN1+gelu, layer-2 -> h2t LDS; phase B as before.
__global__ __launch_bounds__(256) void k_pool2y(
    const float* __restrict__ y1d,
    const float* __restrict__ w2, const float* __restrict__ w3,
    const float* __restrict__ scsh1, const float* __restrict__ scsh2,
    float* __restrict__ stats, float* __restrict__ pooled)
{
    __shared__ __align__(16) float w2s[512];
    __shared__ __align__(16) float w3s[2048];
    __shared__ __align__(16) float h2t[32 * H2LD];
    __shared__ float sc1s[16], sh1s[16], sc2s[32], sh2s[32];
    __shared__ float reds[256];
    __shared__ float redq[256];
    int tid = threadIdx.x;
    for (int i = tid; i < 512; i += 256) w2s[i] = w2[i];
    for (int i = tid; i < 2048; i += 256) w3s[i] = w3[i];
    if (tid < 16) { sc1s[tid] = scsh1[tid]; sh1s[tid] = scsh1[16 + tid]; }
    if (tid < 32) { sc2s[tid] = scsh2[tid]; sh2s[tid] = scsh2[32 + tid]; }
    __syncthreads();

    const float4* w2v = (const float4*)w2s;   // [16][8]
    const float4* w3v = (const float4*)w3s;   // [32][16]

    int lane = tid & 63;
    int pt = tid >> 4;
    int cc = tid & 15;

    float s0 = 0.f, s1 = 0.f, s2 = 0.f, s3 = 0.f;
    float q0 = 0.f, q1 = 0.f, q2 = 0.f, q3 = 0.f;

#pragma unroll 1
    for (int it = 0; it < 4; it++) {
        // ---------- phase A: one row per thread, y1 from dump ----------
        int r = it * 800000 + blockIdx.x * 256 + tid;
        const float* yb = y1d + (size_t)(r >> 6) * 1024 + lane;
        float h1[16];
#pragma unroll
        for (int j = 0; j < 16; j++)
            h1[j] = gelu_f(fmaf(yb[j * 64], sc1s[j], sh1s[j]));
#pragma unroll
        for (int j0 = 0; j0 < 32; j0 += 4) {
            float y0 = 0.f, y1 = 0.f, y2 = 0.f, y3 = 0.f;
#pragma unroll
            for (int i = 0; i < 16; i++) {
                float4 w = w2v[i * 8 + (j0 >> 2)];
                float hi = h1[i];
                y0 = fmaf(hi, w.x, y0); y1 = fmaf(hi, w.y, y1);
                y2 = fmaf(hi, w.z, y2); y3 = fmaf(hi, w.w, y3);
            }
            h2t[(j0 + 0) * H2LD + tid] = gelu_f(fmaf(y0, sc2s[j0 + 0], sh2s[j0 + 0]));
            h2t[(j0 + 1) * H2LD + tid] = gelu_f(fmaf(y1, sc2s[j0 + 1], sh2s[j0 + 1]));
            h2t[(j0 + 2) * H2LD + tid] = gelu_f(fmaf(y2, sc2s[j0 + 2], sh2s[j0 + 2]));
            h2t[(j0 + 3) * H2LD + tid] = gelu_f(fmaf(y3, sc2s[j0 + 3], sh2s[j0 + 3]));
        }
        __syncthreads();

        // ---------- phase B ----------
        float m0 = -3.0e38f, m1 = -3.0e38f, m2 = -3.0e38f, m3 = -3.0e38f;
#pragma unroll 1
        for (int qd = 0; qd < 4; qd++) {
            int rb = (pt << 4) + (qd << 2);
            float a00 = 0.f, a01 = 0.f, a02 = 0.f, a03 = 0.f;
            float a10 = 0.f, a11 = 0.f, a12 = 0.f, a13 = 0.f;
            float a20 = 0.f, a21 = 0.f, a22 = 0.f, a23 = 0.f;
            float a30 = 0.f, a31 = 0.f, a32 = 0.f, a33 = 0.f;
#pragma unroll 8
            for (int i = 0; i < 32; i++) {
                float4 hv = *(const float4*)&h2t[i * H2LD + rb];
                float4 wf = w3v[i * 16 + cc];
                a00 = fmaf(hv.x, wf.x, a00); a01 = fmaf(hv.x, wf.y, a01);
                a02 = fmaf(hv.x, wf.z, a02); a03 = fmaf(hv.x, wf.w, a03);
                a10 = fmaf(hv.y, wf.x, a10); a11 = fmaf(hv.y, wf.y, a11);
                a12 = fmaf(hv.y, wf.z, a12); a13 = fmaf(hv.y, wf.w, a13);
                a20 = fmaf(hv.z, wf.x, a20); a21 = fmaf(hv.z, wf.y, a21);
                a22 = fmaf(hv.z, wf.z, a22); a23 = fmaf(hv.z, wf.w, a23);
                a30 = fmaf(hv.w, wf.x, a30); a31 = fmaf(hv.w, wf.y, a31);
                a32 = fmaf(hv.w, wf.z, a32); a33 = fmaf(hv.w, wf.w, a33);
            }
            m0 = fmaxf(fmaxf(fmaxf(m0, a00), fmaxf(a10, a20)), a30);
            m1 = fmaxf(fmaxf(fmaxf(m1, a01), fmaxf(a11, a21)), a31);
            m2 = fmaxf(fmaxf(fmaxf(m2, a02), fmaxf(a12, a22)), a32);
            m3 = fmaxf(fmaxf(fmaxf(m3, a03), fmaxf(a13, a23)), a33);
        }
        int np = it * 50000 + blockIdx.x * 16 + pt;
        *(float4*)&pooled[(size_t)np * 64 + cc * 4] = make_float4(m0, m1, m2, m3);
        s0 += m0; q0 = fmaf(m0, m0, q0);
        s1 += m1; q1 = fmaf(m1, m1, q1);
        s2 += m2; q2 = fmaf(m2, m2, q2);
        s3 += m3; q3 = fmaf(m3, m3, q3);
        __syncthreads();
    }

    s0 += __shfl_down(s0, 32); s0 += __shfl_down(s0, 16);
    s1 += __shfl_down(s1, 32); s1 += __shfl_down(s1, 16);
    s2 += __shfl_down(s2, 32); s2 += __shfl_down(s2, 16);
    s3 += __shfl_down(s3, 32); s3 += __shfl_down(s3, 16);
    q0 += __shfl_down(q0, 32); q0 += __shfl_down(q0, 16);
    q1 += __shfl_down(q1, 32); q1 += __shfl_down(q1, 16);
    q2 += __shfl_down(q2, 32); q2 += __shfl_down(q2, 16);
    q3 += __shfl_down(q3, 32); q3 += __shfl_down(q3, 16);
    int wv = tid >> 6;
    if (lane < 16) {
        reds[wv * 64 + lane * 4 + 0] = s0;
        reds[wv * 64 + lane * 4 + 1] = s1;
        reds[wv * 64 + lane * 4 + 2] = s2;
        reds[wv * 64 + lane * 4 + 3] = s3;
        redq[wv * 64 + lane * 4 + 0] = q0;
        redq[wv * 64 + lane * 4 + 1] = q1;
        redq[wv * 64 + lane * 4 + 2] = q2;
        redq[wv * 64 + lane * 4 + 3] = q3;
    }
    __syncthreads();
    if (tid < 64) {
        atomicAdd(&stats[tid],
                  reds[tid] + reds[64 + tid] + reds[128 + tid] + reds[192 + tid]);
        atomicAdd(&stats[64 + tid],
                  redq[tid] + redq[64 + tid] + redq[128 + tid] + redq[192 + tid]);
    }
}

// ================= FALLBACK (round-7) PATH: gather-based =================
__global__ __launch_bounds__(256) void k_s1g(
    const float4* __restrict__ pk, const int* __restrict__ gidx,
    float* __restrict__ stats)
{
    __shared__ float red[4 * 35];
    float acc[35];
#pragma unroll
    for (int c = 0; c < 35; c++) acc[c] = 0.f;
    int stride = gridDim.x * 256;
    for (int r = blockIdx.x * 256 + threadIdx.x; r < MROWS; r += stride) {
        int n = r >> 4;
        int idx = gidx[r];
        float4 pa = pk[2 * idx];
        float4 fb = pk[2 * idx + 1];
        float4 pc = pk[2 * n];
        float x[7];
        x[0] = pa.x - pc.x; x[1] = pa.y - pc.y; x[2] = pa.z - pc.z;
        x[3] = fb.x; x[4] = fb.y; x[5] = fb.z; x[6] = fb.w;
#pragma unroll
        for (int i = 0; i < 7; i++) acc[i] += x[i];
        int t = 7;
#pragma unroll
        for (int i = 0; i < 7; i++)
#pragma unroll
            for (int l = i; l < 7; l++) { acc[t] = fmaf(x[i], x[l], acc[t]); t++; }
    }
    int lane = threadIdx.x & 63, wv = threadIdx.x >> 6;
#pragma unroll
    for (int c = 0; c < 35; c++) {
        float v = acc[c];
        v += __shfl_down(v, 32); v += __shfl_down(v, 16); v += __shfl_down(v, 8);
        v += __shfl_down(v, 4);  v += __shfl_down(v, 2);  v += __shfl_down(v, 1);
        if (lane == 0) red[wv * 35 + c] = v;
    }
    __syncthreads();
    for (int c = threadIdx.x; c < 35; c += 256)
        atomicAdd(&stats[c], red[c] + red[35 + c] + red[70 + c] + red[105 + c]);
}

__global__ void k_f1g(const float* __restrict__ stats, const float* __restrict__ w1,
                      const float* __restrict__ g, const float* __restrict__ b,
                      float* __restrict__ scsh)
{
    int j = threadIdx.x;
    if (j < 16) {
        const float invM = 1.0f / (float)MROWS;
        float w[7];
#pragma unroll
        for (int i = 0; i < 7; i++) w[i] = w1[i * 16 + j];
        float m = 0.f;
#pragma unroll
        for (int i = 0; i < 7; i++) m = fmaf(w[i], stats[i], m);
        m *= invM;
        float e2 = 0.f;
        int t = 7;
#pragma unroll
        for (int i = 0; i < 7; i++)
#pragma unroll
            for (int l = i; l < 7; l++) {
                float coeff = (i == l) ? 1.0f : 2.0f;
                e2 = fmaf(coeff * w[i] * w[l], stats[t], e2);
                t++;
            }
        e2 *= invM;
        float v = e2 - m * m;
        float sc = g[j] * rsqrtf(v + EPSB);
        scsh[j] = sc;
        scsh[16 + j] = fmaf(-m, sc, b[j]);
    }
}

template <int PASS>
__global__ __launch_bounds__(256) void k_s2g(
    const float4* __restrict__ pk, const int* __restrict__ gidx,
    const float* __restrict__ w1, const float* __restrict__ scsh1,
    float* __restrict__ stats)
{
    constexpr int NA = (PASS == 0) ? 81 : 71;
    __shared__ __align__(16) float w1s[112];
    __shared__ float sc1s[16], sh1s[16];
    __shared__ float red[4 * NA];
    for (int i = threadIdx.x; i < 112; i += 256) w1s[i] = w1[i];
    if (threadIdx.x < 16) {
        sc1s[threadIdx.x] = scsh1[threadIdx.x];
        sh1s[threadIdx.x] = scsh1[16 + threadIdx.x];
    }
    __syncthreads();
    const float4* w1v = (const float4*)w1s;

    float acc[NA];
#pragma unroll
    for (int c = 0; c < NA; c++) acc[c] = 0.f;

    int stride = gridDim.x * 256;
    for (int r = blockIdx.x * 256 + threadIdx.x; r < MROWS; r += stride) {
        int n = r >> 4;
        int idx = gidx[r];
        float4 pa = pk[2 * idx];
        float4 fb = pk[2 * idx + 1];
        float4 pc = pk[2 * n];
        float x[7];
        x[0] = pa.x - pc.x; x[1] = pa.y - pc.y; x[2] = pa.z - pc.z;
        x[3] = fb.x; x[4] = fb.y; x[5] = fb.z; x[6] = fb.w;
        float h1[16];
#pragma unroll
        for (int j0 = 0; j0 < 16; j0 += 4) {
            float y0 = 0.f, y1 = 0.f, y2 = 0.f, y3 = 0.f;
#pragma unroll
            for (int i = 0; i < 7; i++) {
                float4 w = w1v[i * 4 + (j0 >> 2)];
                float xi = x[i];
                y0 = fmaf(xi, w.x, y0); y1 = fmaf(xi, w.y, y1);
                y2 = fmaf(xi, w.z, y2); y3 = fmaf(xi, w.w, y3);
            }
            h1[j0 + 0] = gelu_f(fmaf(y0, sc1s[j0 + 0], sh1s[j0 + 0]));
            h1[j0 + 1] = gelu_f(fmaf(y1, sc1s[j0 + 1], sh1s[j0 + 1]));
            h1[j0 + 2] = gelu_f(fmaf(y2, sc1s[j0 + 2], sh1s[j0 + 2]));
            h1[j0 + 3] = gelu_f(fmaf(y3, sc1s[j0 + 3], sh1s[j0 + 3]));
        }
        if (PASS == 0) {
            int t = 0;
#pragma unroll
            for (int i = 0; i < 6; i++)
#pragma unroll
                for (int l = i; l < 16; l++) { acc[t] = fmaf(h1[i], h1[l], acc[t]); t++; }
        } else {
#pragma unroll
            for (int i = 0; i < 16; i++) acc[i] += h1[i];
            int t = 16;
#pragma unroll
            for (int i = 6; i < 16; i++)
#pragma unroll
                for (int l = i; l < 16; l++) { acc[t] = fmaf(h1[i], h1[l], acc[t]); t++; }
        }
    }
    int lane = threadIdx.x & 63, wv = threadIdx.x >> 6;
#pragma unroll
    for (int c = 0; c < NA; c++) {
        float v = acc[c];
        v += __shfl_down(v, 32); v += __shfl_down(v, 16); v += __shfl_down(v, 8);
        v += __shfl_down(v, 4);  v += __shfl_down(v, 2);  v += __shfl_down(v, 1);
        if (lane == 0) red[wv * NA + c] = v;
    }
    __syncthreads();
    int base = (PASS == 0) ? 0 : 81;
    for (int c = threadIdx.x; c < NA; c += 256)
        atomicAdd(&stats[base + c], red[c] + red[NA + c] + red[2 * NA + c] + red[3 * NA + c]);
}

__global__ __launch_bounds__(256) void k_pool2g(
    const float* __restrict__ p, const float4* __restrict__ f,
    const int* __restrict__ gidx,
    const float* __restrict__ w1, const float* __restrict__ w2,
    const float* __restrict__ w3,
    const float* __restrict__ scsh1, const float* __restrict__ scsh2,
    float* __restrict__ stats, float* __restrict__ pooled)
{
    __shared__ __align__(16) float w1s[112];
    __shared__ __align__(16) float w2s[512];
    __shared__ __align__(16) float w3s[2048];
    __shared__ __align__(16) float h2t[32 * H2LD];
    __shared__ float sc1s[16], sh1s[16], sc2s[32], sh2s[32];
    __shared__ float reds[256];
    __shared__ float redq[256];
    int tid = threadIdx.x;
    for (int i = tid; i < 112; i += 256) w1s[i] = w1[i];
    for (int i = tid; i < 512; i += 256) w2s[i] = w2[i];
    for (int i = tid; i < 2048; i += 256) w3s[i] = w3[i];
    if (tid < 16) { sc1s[tid] = scsh1[tid]; sh1s[tid] = scsh1[16 + tid]; }
    if (tid < 32) { sc2s[tid] = scsh2[tid]; sh2s[tid] = scsh2[32 + tid]; }
    __syncthreads();

    const float4* w1v = (const float4*)w1s;
    const float4* w2v = (const float4*)w2s;
    const float4* w3v = (const float4*)w3s;

    int lane = tid & 63;
    int pt = tid >> 4;
    int cc = tid & 15;

    float s0 = 0.f, s1 = 0.f, s2 = 0.f, s3 = 0.f;
    float q0 = 0.f, q1 = 0.f, q2 = 0.f, q3 = 0.f;

#pragma unroll 1
    for (int it = 0; it < 4; it++) {
        int r = it * 800000 + blockIdx.x * 256 + tid;
        int n = r >> 4;
        int idx = gidx[r];
        float4 fv = f[idx];
        float x[7];
        x[0] = p[idx * 3 + 0] - p[n * 3 + 0];
        x[1] = p[idx * 3 + 1] - p[n * 3 + 1];
        x[2] = p[idx * 3 + 2] - p[n * 3 + 2];
        x[3] = fv.x; x[4] = fv.y; x[5] = fv.z; x[6] = fv.w;

        float h1[16];
#pragma unroll
        for (int j0 = 0; j0 < 16; j0 += 4) {
            float y0 = 0.f, y1 = 0.f, y2 = 0.f, y3 = 0.f;
#pragma unroll
            for (int i = 0; i < 7; i++) {
                float4 w = w1v[i * 4 + (j0 >> 2)];
                float xi = x[i];
                y0 = fmaf(xi, w.x, y0); y1 = fmaf(xi, w.y, y1);
                y2 = fmaf(xi, w.z, y2); y3 = fmaf(xi, w.w, y3);
            }
            h1[j0 + 0] = gelu_f(fmaf(y0, sc1s[j0 + 0], sh1s[j0 + 0]));
            h1[j0 + 1] = gelu_f(fmaf(y1, sc1s[j0 + 1], sh1s[j0 + 1]));
            h1[j0 + 2] = gelu_f(fmaf(y2, sc1s[j0 + 2], sh1s[j0 + 2]));
            h1[j0 + 3] = gelu_f(fmaf(y3, sc1s[j0 + 3], sh1s[j0 + 3]));
        }
#pragma unroll
        for (int j0 = 0; j0 < 32; j0 += 4) {
            float y0 = 0.f, y1 = 0.f, y2 = 0.f, y3 = 0.f;
#pragma unroll
            for (int i = 0; i < 16; i++) {
                float4 w = w2v[i * 8 + (j0 >> 2)];
                float hi = h1[i];
                y0 = fmaf(hi, w.x, y0); y1 = fmaf(hi, w.y, y1);
                y2 = fmaf(hi, w.z, y2); y3 = fmaf(hi, w.w, y3);
            }
            h2t[(j0 + 0) * H2LD + tid] = gelu_f(fmaf(y0, sc2s[j0 + 0], sh2s[j0 + 0]));
            h2t[(j0 + 1) * H2LD + tid] = gelu_f(fmaf(y1, sc2s[j0 + 1], sh2s[j0 + 1]));
            h2t[(j0 + 2) * H2LD + tid] = gelu_f(fmaf(y2, sc2s[j0 + 2], sh2s[j0 + 2]));
            h2t[(j0 + 3) * H2LD + tid] = gelu_f(fmaf(y3, sc2s[j0 + 3], sh2s[j0 + 3]));
        }
        __syncthreads();

        float m0 = -3.0e38f, m1 = -3.0e38f, m2 = -3.0e38f, m3 = -3.0e38f;
#pragma unroll 1
        for (int qd = 0; qd < 4; qd++) {
            int rb = (pt << 4) + (qd << 2);
            float a00 = 0.f, a01 = 0.f, a02 = 0.f, a03 = 0.f;
            float a10 = 0.f, a11 = 0.f, a12 = 0.f, a13 = 0.f;
            float a20 = 0.f, a21 = 0.f, a22 = 0.f, a23 = 0.f;
            float a30 = 0.f, a31 = 0.f, a32 = 0.f, a33 = 0.f;
#pragma unroll 8
            for (int i = 0; i < 32; i++) {
                float4 hv = *(const float4*)&h2t[i * H2LD + rb];
                float4 wf = w3v[i * 16 + cc];
                a00 = fmaf(hv.x, wf.x, a00); a01 = fmaf(hv.x, wf.y, a01);
                a02 = fmaf(hv.x, wf.z, a02); a03 = fmaf(hv.x, wf.w, a03);
                a10 = fmaf(hv.y, wf.x, a10); a11 = fmaf(hv.y, wf.y, a11);
                a12 = fmaf(hv.y, wf.z, a12); a13 = fmaf(hv.y, wf.w, a13);
                a20 = fmaf(hv.z, wf.x, a20); a21 = fmaf(hv.z, wf.y, a21);
                a22 = fmaf(hv.z, wf.z, a22); a23 = fmaf(hv.z, wf.w, a23);
                a30 = fmaf(hv.w, wf.x, a30); a31 = fmaf(hv.w, wf.y, a31);
                a32 = fmaf(hv.w, wf.z, a32); a33 = fmaf(hv.w, wf.w, a33);
            }
            m0 = fmaxf(fmaxf(fmaxf(m0, a00), fmaxf(a10, a20)), a30);
            m1 = fmaxf(fmaxf(fmaxf(m1, a01), fmaxf(a11, a21)), a31);
            m2 = fmaxf(fmaxf(fmaxf(m2, a02), fmaxf(a12, a22)), a32);
            m3 = fmaxf(fmaxf(fmaxf(m3, a03), fmaxf(a13, a23)), a33);
        }
        int np = it * 50000 + blockIdx.x * 16 + pt;
        *(float4*)&pooled[(size_t)np * 64 + cc * 4] = make_float4(m0, m1, m2, m3);
        s0 += m0; q0 = fmaf(m0, m0, q0);
        s1 += m1; q1 = fmaf(m1, m1, q1);
        s2 += m2; q2 = fmaf(m2, m2, q2);
        s3 += m3; q3 = fmaf(m3, m3, q3);
        __syncthreads();
    }

    s0 += __shfl_down(s0, 32); s0 += __shfl_down(s0, 16);
    s1 += __shfl_down(s1, 32); s1 += __shfl_down(s1, 16);
    s2 += __shfl_down(s2, 32); s2 += __shfl_down(s2, 16);
    s3 += __shfl_down(s3, 32); s3 += __shfl_down(s3, 16);
    q0 += __shfl_down(q0, 32); q0 += __shfl_down(q0, 16);
    q1 += __shfl_down(q1, 32); q1 += __shfl_down(q1, 16);
    q2 += __shfl_down(q2, 32); q2 += __shfl_down(q2, 16);
    q3 += __shfl_down(q3, 32); q3 += __shfl_down(q3, 16);
    int wv = tid >> 6;
    if (lane < 16) {
        reds[wv * 64 + lane * 4 + 0] = s0;
        reds[wv * 64 + lane * 4 + 1] = s1;
        reds[wv * 64 + lane * 4 + 2] = s2;
        reds[wv * 64 + lane * 4 + 3] = s3;
        redq[wv * 64 + lane * 4 + 0] = q0;
        redq[wv * 64 + lane * 4 + 1] = q1;
        redq[wv * 64 + lane * 4 + 2] = q2;
        redq[wv * 64 + lane * 4 + 3] = q3;
    }
    __syncthreads();
    if (tid < 64) {
        atomicAdd(&stats[tid],
                  reds[tid] + reds[64 + tid] + reds[128 + tid] + reds[192 + tid]);
        atomicAdd(&stats[64 + tid],
                  redq[tid] + redq[64 + tid] + redq[128 + tid] + redq[192 + tid]);
    }
}

// double-BN collapse
__global__ void k_fin3(const float* __restrict__ stats,
                       const float* __restrict__ g_nbr, const float* __restrict__ g_post,
                       const float* __restrict__ b_post, float* __restrict__ scsh)
{
    int j = threadIdx.x;
    if (j < 64) {
        float m = stats[j] * (1.0f / NPTS);
        float v = stats[64 + j] * (1.0f / NPTS) - m * m;
        float a1 = g_nbr[j] * rsqrtf(v + EPSB);
        float s3 = g_post[j] * a1 * rsqrtf(fmaf(a1 * a1, v, EPSB));
        scsh[j] = s3;
        scsh[64 + j] = fmaf(-m, s3, b_post[j]);
    }
}

// head: (N x 64) @ (64 x 256)
__global__ __launch_bounds__(256) void k_head(
    const float* __restrict__ pooled, const float* __restrict__ scsh3,
    const float* __restrict__ wpost, float* __restrict__ out)
{
    __shared__ float rowbuf[512];
    __shared__ float s3s[64], c3s[64];
    int tid = threadIdx.x;
    if (tid < 64) { s3s[tid] = scsh3[tid]; c3s[tid] = scsh3[64 + tid]; }
    float wcol[64];
#pragma unroll
    for (int j = 0; j < 64; j++) wcol[j] = wpost[j * 256 + tid];
    __syncthreads();

    const int nchunks = NPTS / 8;  // 25000
    for (int c = blockIdx.x; c < nchunks; c += gridDim.x) {
        int n0 = c * 8;
#pragma unroll
        for (int t = tid; t < 512; t += 256) {
            int rr = t >> 6, j = t & 63;
            rowbuf[t] = fmaf(pooled[(size_t)(n0 + rr) * 64 + j], s3s[j], c3s[j]);
        }
        __syncthreads();
#pragma unroll
        for (int rr = 0; rr < 8; rr++) {
            float acc = 0.f;
#pragma unroll
            for (int j = 0; j < 64; j++) acc = fmaf(rowbuf[rr * 64 + j], wcol[j], acc);
            out[(size_t)(n0 + rr) * 256 + tid] = acc;
        }
        __syncthreads();
    }
}

extern "C" void kernel_launch(void* const* d_in, const int* in_sizes, int n_in,
                              void* d_out, int out_size, void* d_ws, size_t ws_size,
                              hipStream_t stream)
{
    const float*  p    = (const float*)d_in[0];
    const float4* f    = (const float4*)d_in[1];
    const int*    gidx = (const int*)d_in[2];
    const float*  w1   = (const float*)d_in[3];
    const float*  g1   = (const float*)d_in[4];
    const float*  b1   = (const float*)d_in[5];
    const float*  w2   = (const float*)d_in[6];
    const float*  g2   = (const float*)d_in[7];
    const float*  b2   = (const float*)d_in[8];
    const float*  w3   = (const float*)d_in[9];
    const float*  gn   = (const float*)d_in[10];
    // d_in[11] = b_nbr: cancels exactly in the collapsed double-BN
    const float*  gp   = (const float*)d_in[12];
    const float*  bp   = (const float*)d_in[13];
    const float*  wp   = (const float*)d_in[14];
    float* out = (float*)d_out;
    float* ws  = (float*)d_ws;

    float* stats1 = ws;          // 35 floats max
    float* scsh1  = ws + 40;     // 32
    float* stats2 = ws + 80;     // 152 floats
    float* scsh2  = ws + 240;    // 64
    float* stats3 = ws + 304;    // 128
    float* scsh3  = ws + 432;    // 128
    float* pooled = ws + 1024;               // 12.8M floats (51.2 MB)
    float4* pk    = (float4*)(ws + 1024);    // aliases pooled (dead before pool writes)
    float* y1d    = ws + 1024 + 12800000;    // 51.2M floats (204.8 MB)

    // big path needs: (1024 + 12.8M + 51.2M) floats = 256.005 MB
    const size_t need = ((size_t)1024 + 12800000 + 51200000) * 4;

    hipMemsetAsync(d_ws, 0, 2048, stream);
    k_pack<<<(NPTS + 255) / 256, 256, 0, stream>>>(p, f, pk);

    if (ws_size >= need) {
        // ONE gather pass -> y1 dump; everything downstream streams coalesced.
        k_gy1<<<2048, 256, 0, stream>>>(pk, gidx, w1, stats1, y1d);
        k_fin1b<<<1, 64, 0, stream>>>(stats1, g1, b1, scsh1);
        k_momA<<<2048, 256, 0, stream>>>(y1d, scsh1, stats2);
        k_momB<<<2048, 256, 0, stream>>>(y1d, scsh1, stats2);
        k_fin2<<<1, 64, 0, stream>>>(stats2, w2, g2, b2, scsh2);
        k_pool2y<<<3125, 256, 0, stream>>>(y1d, w2, w3, scsh1, scsh2, stats3, pooled);
    } else {
        // fallback = round-7 verified path
        k_s1g<<<2048, 256, 0, stream>>>(pk, gidx, stats1);
        k_f1g<<<1, 64, 0, stream>>>(stats1, w1, g1, b1, scsh1);
        k_s2g<0><<<2048, 256, 0, stream>>>(pk, gidx, w1, scsh1, stats2);
        k_s2g<1><<<2048, 256, 0, stream>>>(pk, gidx, w1, scsh1, stats2);
        k_fin2<<<1, 64, 0, stream>>>(stats2, w2, g2, b2, scsh2);
        k_pool2g<<<3125, 256, 0, stream>>>(p, f, gidx, w1, w2, w3, scsh1, scsh2, stats3, pooled);
    }
    k_fin3<<<1, 64, 0, stream>>>(stats3, gn, gp, bp, scsh3);
    k_head<<<1024, 256, 0, stream>>>(pooled, scsh3, wp, out);
}

// Round 9
// 1260.521 us; speedup vs baseline: 1.0209x; 1.0166x over previous
//
#include <hip/hip_runtime.h>
#include <cmath>

#define NPTS  200000
#define KNBR  16
#define MROWS 3200000   // NPTS*KNBR
#define EPSB  1e-5f
#define H2LD  260       // h2t row stride in floats

__device__ __forceinline__ float gelu_f(float x) {
    return 0.5f * x * (1.0f + erff(x * 0.70710678118654752f));
}

// ---------------- pack p (12B) + f (16B) into one 32B record per point ----------------
__global__ __launch_bounds__(256) void k_pack(
    const float* __restrict__ p, const float4* __restrict__ f,
    float4* __restrict__ pk)
{
    int n = blockIdx.x * 256 + threadIdx.x;
    if (n < NPTS) {
        float4 a;
        a.x = p[n * 3 + 0]; a.y = p[n * 3 + 1]; a.z = p[n * 3 + 2]; a.w = 0.f;
        pk[2 * n]     = a;
        pk[2 * n + 1] = f[n];
    }
}

// ================= BIG-WORKSPACE PATH =================
// ONE gather pass: y1 = x@w1 per row, BN1 sums, dump y1 in 64-row-tiled
// column-major layout (fully coalesced stores/loads).
__global__ __launch_bounds__(256) void k_gy1(
    const float4* __restrict__ pk, const int* __restrict__ gidx,
    const float* __restrict__ w1, float* __restrict__ stats,
    float* __restrict__ y1d)
{
    __shared__ __align__(16) float w1s[112];
    __shared__ float red[4 * 32];
    for (int i = threadIdx.x; i < 112; i += 256) w1s[i] = w1[i];
    __syncthreads();
    const float4* w1v = (const float4*)w1s;   // [7][4]

    float acc[32];
#pragma unroll
    for (int c = 0; c < 32; c++) acc[c] = 0.f;

    int tid = threadIdx.x;
    int lr = tid & 63;
    int stride = gridDim.x * 256;
    for (int r = blockIdx.x * 256 + tid; r < MROWS; r += stride) {
        int n = r >> 4;
        int idx = gidx[r];
        float4 pa = pk[2 * idx];
        float4 fb = pk[2 * idx + 1];
        float4 pc = pk[2 * n];
        float x[7];
        x[0] = pa.x - pc.x; x[1] = pa.y - pc.y; x[2] = pa.z - pc.z;
        x[3] = fb.x; x[4] = fb.y; x[5] = fb.z; x[6] = fb.w;
        float* yb = y1d + (size_t)(r >> 6) * 1024 + lr;
#pragma unroll
        for (int j0 = 0; j0 < 16; j0 += 4) {
            float y0 = 0.f, y1 = 0.f, y2 = 0.f, y3 = 0.f;
#pragma unroll
            for (int i = 0; i < 7; i++) {
                float4 w = w1v[i * 4 + (j0 >> 2)];
                float xi = x[i];
                y0 = fmaf(xi, w.x, y0); y1 = fmaf(xi, w.y, y1);
                y2 = fmaf(xi, w.z, y2); y3 = fmaf(xi, w.w, y3);
            }
            yb[(j0 + 0) * 64] = y0; yb[(j0 + 1) * 64] = y1;
            yb[(j0 + 2) * 64] = y2; yb[(j0 + 3) * 64] = y3;
            acc[j0 + 0] += y0; acc[16 + j0 + 0] += y0 * y0;
            acc[j0 + 1] += y1; acc[16 + j0 + 1] += y1 * y1;
            acc[j0 + 2] += y2; acc[16 + j0 + 2] += y2 * y2;
            acc[j0 + 3] += y3; acc[16 + j0 + 3] += y3 * y3;
        }
    }
    int lane = tid & 63, wv = tid >> 6;
#pragma unroll
    for (int c = 0; c < 32; c++) {
        float v = acc[c];
        v += __shfl_down(v, 32); v += __shfl_down(v, 16); v += __shfl_down(v, 8);
        v += __shfl_down(v, 4);  v += __shfl_down(v, 2);  v += __shfl_down(v, 1);
        if (lane == 0) red[wv * 32 + c] = v;
    }
    __syncthreads();
    for (int c = tid; c < 32; c += 256)
        atomicAdd(&stats[c], red[c] + red[32 + c] + red[64 + c] + red[96 + c]);
}

// BN1 finalize from y1 sums
__global__ void k_fin1b(const float* __restrict__ stats, const float* __restrict__ g,
                        const float* __restrict__ b, float* __restrict__ scsh)
{
    int j = threadIdx.x;
    if (j < 16) {
        const float invM = 1.0f / (float)MROWS;
        float m = stats[j] * invM;
        float v = stats[16 + j] * invM - m * m;
        float sc = g[j] * rsqrtf(v + EPSB);
        scsh[j] = sc;
        scsh[16 + j] = fmaf(-m, sc, b[j]);
    }
}

// h1 moments pass A from the y1 dump: pairs (i,l), 0<=i<6, i<=l<16 -> 81.
__global__ __launch_bounds__(256) void k_momA(
    const float* __restrict__ y1d, const float* __restrict__ scsh1,
    float* __restrict__ stats)
{
    __shared__ float sc1s[16], sh1s[16];
    __shared__ float red[4 * 81];
    if (threadIdx.x < 16) {
        sc1s[threadIdx.x] = scsh1[threadIdx.x];
        sh1s[threadIdx.x] = scsh1[16 + threadIdx.x];
    }
    __syncthreads();

    float acc[81];
#pragma unroll
    for (int c = 0; c < 81; c++) acc[c] = 0.f;

    int tid = threadIdx.x;
    int lr = tid & 63;
    int stride = gridDim.x * 256;
    for (int r = blockIdx.x * 256 + tid; r < MROWS; r += stride) {
        const float* yb = y1d + (size_t)(r >> 6) * 1024 + lr;
        float h1[16];
#pragma unroll
        for (int j = 0; j < 16; j++)
            h1[j] = gelu_f(fmaf(yb[j * 64], sc1s[j], sh1s[j]));
        int t = 0;
#pragma unroll
        for (int i = 0; i < 6; i++)
#pragma unroll
            for (int l = i; l < 16; l++) { acc[t] = fmaf(h1[i], h1[l], acc[t]); t++; }
    }
    int lane = tid & 63, wv = tid >> 6;
#pragma unroll
    for (int c = 0; c < 81; c++) {
        float v = acc[c];
        v += __shfl_down(v, 32); v += __shfl_down(v, 16); v += __shfl_down(v, 8);
        v += __shfl_down(v, 4);  v += __shfl_down(v, 2);  v += __shfl_down(v, 1);
        if (lane == 0) red[wv * 81 + c] = v;
    }
    __syncthreads();
    for (int c = tid; c < 81; c += 256)
        atomicAdd(&stats[c], red[c] + red[81 + c] + red[162 + c] + red[243 + c]);
}

// h1 moments pass B from the y1 dump: sums (16) + pairs 6<=i<=l<16 (55)
__global__ __launch_bounds__(256) void k_momB(
    const float* __restrict__ y1d, const float* __restrict__ scsh1,
    float* __restrict__ stats)
{
    __shared__ float sc1s[16], sh1s[16];
    __shared__ float red[4 * 71];
    if (threadIdx.x < 16) {
        sc1s[threadIdx.x] = scsh1[threadIdx.x];
        sh1s[threadIdx.x] = scsh1[16 + threadIdx.x];
    }
    __syncthreads();

    float acc[71];
#pragma unroll
    for (int c = 0; c < 71; c++) acc[c] = 0.f;

    int tid = threadIdx.x;
    int lr = tid & 63;
    int stride = gridDim.x * 256;
    for (int r = blockIdx.x * 256 + tid; r < MROWS; r += stride) {
        const float* yb = y1d + (size_t)(r >> 6) * 1024 + lr;
        float h1[16];
#pragma unroll
        for (int j = 0; j < 16; j++)
            h1[j] = gelu_f(fmaf(yb[j * 64], sc1s[j], sh1s[j]));
#pragma unroll
        for (int i = 0; i < 16; i++) acc[i] += h1[i];
        int t = 16;
#pragma unroll
        for (int i = 6; i < 16; i++)
#pragma unroll
            for (int l = i; l < 16; l++) { acc[t] = fmaf(h1[i], h1[l], acc[t]); t++; }
    }
    int lane = tid & 63, wv = tid >> 6;
#pragma unroll
    for (int c = 0; c < 71; c++) {
        float v = acc[c];
        v += __shfl_down(v, 32); v += __shfl_down(v, 16); v += __shfl_down(v, 8);
        v += __shfl_down(v, 4);  v += __shfl_down(v, 2);  v += __shfl_down(v, 1);
        if (lane == 0) red[wv * 71 + c] = v;
    }
    __syncthreads();
    for (int c = tid; c < 71; c += 256)
        atomicAdd(&stats[81 + c], red[c] + red[71 + c] + red[142 + c] + red[213 + c]);
}

// BN2 finalize from h1 moments
__global__ void k_fin2(const float* __restrict__ stats, const float* __restrict__ w2,
                       const float* __restrict__ g, const float* __restrict__ b,
                       float* __restrict__ scsh)
{
    int j = threadIdx.x;
    if (j < 32) {
        const float invM = 1.0f / (float)MROWS;
        float w[16];
#pragma unroll
        for (int i = 0; i < 16; i++) w[i] = w2[i * 32 + j];
        float m = 0.f;
#pragma unroll
        for (int i = 0; i < 16; i++) m = fmaf(w[i], stats[81 + i], m);
        m *= invM;
        float e2 = 0.f;
        int t = 0;
#pragma unroll
        for (int i = 0; i < 6; i++)
#pragma unroll
            for (int l = i; l < 16; l++) {
                float coeff = (i == l) ? 1.0f : 2.0f;
                e2 = fmaf(coeff * w[i] * w[l], stats[t], e2);
                t++;
            }
        t = 97;
#pragma unroll
        for (int i = 6; i < 16; i++)
#pragma unroll
            for (int l = i; l < 16; l++) {
                float coeff = (i == l) ? 1.0f : 2.0f;
                e2 = fmaf(coeff * w[i] * w[l], stats[t], e2);
                t++;
            }
        e2 *= invM;
        float v = e2 - m * m;
        float sc = g[j] * rsqrtf(v + EPSB);
        scsh[j] = sc;
        scsh[32 + j] = fmaf(-m, sc, b[j]);
    }
}

// Two-phase pool kernel, y1-dump variant.
// Phase B LOOP-INTERCHANGED: i (h2 channel) outer; per i read w3 frag ONCE and
// the 16 neighbor values as 4x float4; accumulate into a[16][4] register tile.
// DS reads drop 512 -> 160 b128/thread/iter; phase B becomes VALU-bound.
__global__ __launch_bounds__(256) void k_pool2y(
    const float* __restrict__ y1d,
    const float* __restrict__ w2, const float* __restrict__ w3,
    const float* __restrict__ scsh1, const float* __restrict__ scsh2,
    float* __restrict__ stats, float* __restrict__ pooled)
{
    __shared__ __align__(16) float w2s[512];
    __shared__ __align__(16) float w3s[2048];
    __shared__ __align__(16) float h2t[32 * H2LD];
    __shared__ float sc1s[16], sh1s[16], sc2s[32], sh2s[32];
    __shared__ float reds[256];
    __shared__ float redq[256];
    int tid = threadIdx.x;
    for (int i = tid; i < 512; i += 256) w2s[i] = w2[i];
    for (int i = tid; i < 2048; i += 256) w3s[i] = w3[i];
    if (tid < 16) { sc1s[tid] = scsh1[tid]; sh1s[tid] = scsh1[16 + tid]; }
    if (tid < 32) { sc2s[tid] = scsh2[tid]; sh2s[tid] = scsh2[32 + tid]; }
    __syncthreads();

    const float4* w2v = (const float4*)w2s;   // [16][8]
    const float4* w3v = (const float4*)w3s;   // [32][16]

    int lane = tid & 63;
    int pt = tid >> 4;
    int cc = tid & 15;

    float s0 = 0.f, s1 = 0.f, s2 = 0.f, s3 = 0.f;
    float q0 = 0.f, q1 = 0.f, q2 = 0.f, q3 = 0.f;

#pragma unroll 1
    for (int it = 0; it < 4; it++) {
        // ---------- phase A: one row per thread, y1 from dump ----------
        int r = it * 800000 + blockIdx.x * 256 + tid;
        const float* yb = y1d + (size_t)(r >> 6) * 1024 + lane;
        float h1[16];
#pragma unroll
        for (int j = 0; j < 16; j++)
            h1[j] = gelu_f(fmaf(yb[j * 64], sc1s[j], sh1s[j]));
#pragma unroll
        for (int j0 = 0; j0 < 32; j0 += 4) {
            float y0 = 0.f, y1 = 0.f, y2 = 0.f, y3 = 0.f;
#pragma unroll
            for (int i = 0; i < 16; i++) {
                float4 w = w2v[i * 8 + (j0 >> 2)];
                float hi = h1[i];
                y0 = fmaf(hi, w.x, y0); y1 = fmaf(hi, w.y, y1);
                y2 = fmaf(hi, w.z, y2); y3 = fmaf(hi, w.w, y3);
            }
            h2t[(j0 + 0) * H2LD + tid] = gelu_f(fmaf(y0, sc2s[j0 + 0], sh2s[j0 + 0]));
            h2t[(j0 + 1) * H2LD + tid] = gelu_f(fmaf(y1, sc2s[j0 + 1], sh2s[j0 + 1]));
            h2t[(j0 + 2) * H2LD + tid] = gelu_f(fmaf(y2, sc2s[j0 + 2], sh2s[j0 + 2]));
            h2t[(j0 + 3) * H2LD + tid] = gelu_f(fmaf(y3, sc2s[j0 + 3], sh2s[j0 + 3]));
        }
        __syncthreads();

        // ---------- phase B: i-outer, a[16][4] register tile ----------
        float a[16][4];
#pragma unroll
        for (int t = 0; t < 16; t++) {
            a[t][0] = 0.f; a[t][1] = 0.f; a[t][2] = 0.f; a[t][3] = 0.f;
        }
        int rb0 = pt << 4;
#pragma unroll 8
        for (int i = 0; i < 32; i++) {
            float4 wf = w3v[i * 16 + cc];                 // read ONCE per i
            const float* hrow = &h2t[i * H2LD + rb0];
            float4 hA = *(const float4*)&hrow[0];
            float4 hB = *(const float4*)&hrow[4];
            float4 hC = *(const float4*)&hrow[8];
            float4 hD = *(const float4*)&hrow[12];
            float hn[16] = { hA.x, hA.y, hA.z, hA.w,
                             hB.x, hB.y, hB.z, hB.w,
                             hC.x, hC.y, hC.z, hC.w,
                             hD.x, hD.y, hD.z, hD.w };
#pragma unroll
            for (int t = 0; t < 16; t++) {
                float h = hn[t];
                a[t][0] = fmaf(h, wf.x, a[t][0]);
                a[t][1] = fmaf(h, wf.y, a[t][1]);
                a[t][2] = fmaf(h, wf.z, a[t][2]);
                a[t][3] = fmaf(h, wf.w, a[t][3]);
            }
        }
        float m0 = -3.0e38f, m1 = -3.0e38f, m2 = -3.0e38f, m3 = -3.0e38f;
#pragma unroll
        for (int t = 0; t < 16; t++) {
            m0 = fmaxf(m0, a[t][0]);
            m1 = fmaxf(m1, a[t][1]);
            m2 = fmaxf(m2, a[t][2]);
            m3 = fmaxf(m3, a[t][3]);
        }
        int np = it * 50000 + blockIdx.x * 16 + pt;
        *(float4*)&pooled[(size_t)np * 64 + cc * 4] = make_float4(m0, m1, m2, m3);
        s0 += m0; q0 = fmaf(m0, m0, q0);
        s1 += m1; q1 = fmaf(m1, m1, q1);
        s2 += m2; q2 = fmaf(m2, m2, q2);
        s3 += m3; q3 = fmaf(m3, m3, q3);
        __syncthreads();
    }

    s0 += __shfl_down(s0, 32); s0 += __shfl_down(s0, 16);
    s1 += __shfl_down(s1, 32); s1 += __shfl_down(s1, 16);
    s2 += __shfl_down(s2, 32); s2 += __shfl_down(s2, 16);
    s3 += __shfl_down(s3, 32); s3 += __shfl_down(s3, 16);
    q0 += __shfl_down(q0, 32); q0 += __shfl_down(q0, 16);
    q1 += __shfl_down(q1, 32); q1 += __shfl_down(q1, 16);
    q2 += __shfl_down(q2, 32); q2 += __shfl_down(q2, 16);
    q3 += __shfl_down(q3, 32); q3 += __shfl_down(q3, 16);
    int wv = tid >> 6;
    if (lane < 16) {
        reds[wv * 64 + lane * 4 + 0] = s0;
        reds[wv * 64 + lane * 4 + 1] = s1;
        reds[wv * 64 + lane * 4 + 2] = s2;
        reds[wv * 64 + lane * 4 + 3] = s3;
        redq[wv * 64 + lane * 4 + 0] = q0;
        redq[wv * 64 + lane * 4 + 1] = q1;
        redq[wv * 64 + lane * 4 + 2] = q2;
        redq[wv * 64 + lane * 4 + 3] = q3;
    }
    __syncthreads();
    if (tid < 64) {
        atomicAdd(&stats[tid],
                  reds[tid] + reds[64 + tid] + reds[128 + tid] + reds[192 + tid]);
        atomicAdd(&stats[64 + tid],
                  redq[tid] + redq[64 + tid] + redq[128 + tid] + redq[192 + tid]);
    }
}

// ================= FALLBACK PATH (small workspace; round-7 verified) =================
__global__ __launch_bounds__(256) void k_s1g(
    const float4* __restrict__ pk, const int* __restrict__ gidx,
    float* __restrict__ stats)
{
    __shared__ float red[4 * 35];
    float acc[35];
#pragma unroll
    for (int c = 0; c < 35; c++) acc[c] = 0.f;
    int stride = gridDim.x * 256;
    for (int r = blockIdx.x * 256 + threadIdx.x; r < MROWS; r += stride) {
        int n = r >> 4;
        int idx = gidx[r];
        float4 pa = pk[2 * idx];
        float4 fb = pk[2 * idx + 1];
        float4 pc = pk[2 * n];
        float x[7];
        x[0] = pa.x - pc.x; x[1] = pa.y - pc.y; x[2] = pa.z - pc.z;
        x[3] = fb.x; x[4] = fb.y; x[5] = fb.z; x[6] = fb.w;
#pragma unroll
        for (int i = 0; i < 7; i++) acc[i] += x[i];
        int t = 7;
#pragma unroll
        for (int i = 0; i < 7; i++)
#pragma unroll
            for (int l = i; l < 7; l++) { acc[t] = fmaf(x[i], x[l], acc[t]); t++; }
    }
    int lane = threadIdx.x & 63, wv = threadIdx.x >> 6;
#pragma unroll
    for (int c = 0; c < 35; c++) {
        float v = acc[c];
        v += __shfl_down(v, 32); v += __shfl_down(v, 16); v += __shfl_down(v, 8);
        v += __shfl_down(v, 4);  v += __shfl_down(v, 2);  v += __shfl_down(v, 1);
        if (lane == 0) red[wv * 35 + c] = v;
    }
    __syncthreads();
    for (int c = threadIdx.x; c < 35; c += 256)
        atomicAdd(&stats[c], red[c] + red[35 + c] + red[70 + c] + red[105 + c]);
}

__global__ void k_f1g(const float* __restrict__ stats, const float* __restrict__ w1,
                      const float* __restrict__ g, const float* __restrict__ b,
                      float* __restrict__ scsh)
{
    int j = threadIdx.x;
    if (j < 16) {
        const float invM = 1.0f / (float)MROWS;
        float w[7];
#pragma unroll
        for (int i = 0; i < 7; i++) w[i] = w1[i * 16 + j];
        float m = 0.f;
#pragma unroll
        for (int i = 0; i < 7; i++) m = fmaf(w[i], stats[i], m);
        m *= invM;
        float e2 = 0.f;
        int t = 7;
#pragma unroll
        for (int i = 0; i < 7; i++)
#pragma unroll
            for (int l = i; l < 7; l++) {
                float coeff = (i == l) ? 1.0f : 2.0f;
                e2 = fmaf(coeff * w[i] * w[l], stats[t], e2);
                t++;
            }
        e2 *= invM;
        float v = e2 - m * m;
        float sc = g[j] * rsqrtf(v + EPSB);
        scsh[j] = sc;
        scsh[16 + j] = fmaf(-m, sc, b[j]);
    }
}

template <int PASS>
__global__ __launch_bounds__(256) void k_s2g(
    const float4* __restrict__ pk, const int* __restrict__ gidx,
    const float* __restrict__ w1, const float* __restrict__ scsh1,
    float* __restrict__ stats)
{
    constexpr int NA = (PASS == 0) ? 81 : 71;
    __shared__ __align__(16) float w1s[112];
    __shared__ float sc1s[16], sh1s[16];
    __shared__ float red[4 * NA];
    for (int i = threadIdx.x; i < 112; i += 256) w1s[i] = w1[i];
    if (threadIdx.x < 16) {
        sc1s[threadIdx.x] = scsh1[threadIdx.x];
        sh1s[threadIdx.x] = scsh1[16 + threadIdx.x];
    }
    __syncthreads();
    const float4* w1v = (const float4*)w1s;

    float acc[NA];
#pragma unroll
    for (int c = 0; c < NA; c++) acc[c] = 0.f;

    int stride = gridDim.x * 256;
    for (int r = blockIdx.x * 256 + threadIdx.x; r < MROWS; r += stride) {
        int n = r >> 4;
        int idx = gidx[r];
        float4 pa = pk[2 * idx];
        float4 fb = pk[2 * idx + 1];
        float4 pc = pk[2 * n];
        float x[7];
        x[0] = pa.x - pc.x; x[1] = pa.y - pc.y; x[2] = pa.z - pc.z;
        x[3] = fb.x; x[4] = fb.y; x[5] = fb.z; x[6] = fb.w;
        float h1[16];
#pragma unroll
        for (int j0 = 0; j0 < 16; j0 += 4) {
            float y0 = 0.f, y1 = 0.f, y2 = 0.f, y3 = 0.f;
#pragma unroll
            for (int i = 0; i < 7; i++) {
                float4 w = w1v[i * 4 + (j0 >> 2)];
                float xi = x[i];
                y0 = fmaf(xi, w.x, y0); y1 = fmaf(xi, w.y, y1);
                y2 = fmaf(xi, w.z, y2); y3 = fmaf(xi, w.w, y3);
            }
            h1[j0 + 0] = gelu_f(fmaf(y0, sc1s[j0 + 0], sh1s[j0 + 0]));
            h1[j0 + 1] = gelu_f(fmaf(y1, sc1s[j0 + 1], sh1s[j0 + 1]));
            h1[j0 + 2] = gelu_f(fmaf(y2, sc1s[j0 + 2], sh1s[j0 + 2]));
            h1[j0 + 3] = gelu_f(fmaf(y3, sc1s[j0 + 3], sh1s[j0 + 3]));
        }
        if (PASS == 0) {
            int t = 0;
#pragma unroll
            for (int i = 0; i < 6; i++)
#pragma unroll
                for (int l = i; l < 16; l++) { acc[t] = fmaf(h1[i], h1[l], acc[t]); t++; }
        } else {
#pragma unroll
            for (int i = 0; i < 16; i++) acc[i] += h1[i];
            int t = 16;
#pragma unroll
            for (int i = 6; i < 16; i++)
#pragma unroll
                for (int l = i; l < 16; l++) { acc[t] = fmaf(h1[i], h1[l], acc[t]); t++; }
        }
    }
    int lane = threadIdx.x & 63, wv = threadIdx.x >> 6;
#pragma unroll
    for (int c = 0; c < NA; c++) {
        float v = acc[c];
        v += __shfl_down(v, 32); v += __shfl_down(v, 16); v += __shfl_down(v, 8);
        v += __shfl_down(v, 4);  v += __shfl_down(v, 2);  v += __shfl_down(v, 1);
        if (lane == 0) red[wv * NA + c] = v;
    }
    __syncthreads();
    int base = (PASS == 0) ? 0 : 81;
    for (int c = threadIdx.x; c < NA; c += 256)
        atomicAdd(&stats[base + c], red[c] + red[NA + c] + red[2 * NA + c] + red[3 * NA + c]);
}

__global__ __launch_bounds__(256) void k_pool2g(
    const float* __restrict__ p, const float4* __restrict__ f,
    const int* __restrict__ gidx,
    const float* __restrict__ w1, const float* __restrict__ w2,
    const float* __restrict__ w3,
    const float* __restrict__ scsh1, const float* __restrict__ scsh2,
    float* __restrict__ stats, float* __restrict__ pooled)
{
    __shared__ __align__(16) float w1s[112];
    __shared__ __align__(16) float w2s[512];
    __shared__ __align__(16) float w3s[2048];
    __shared__ __align__(16) float h2t[32 * H2LD];
    __shared__ float sc1s[16], sh1s[16], sc2s[32], sh2s[32];
    __shared__ float reds[256];
    __shared__ float redq[256];
    int tid = threadIdx.x;
    for (int i = tid; i < 112; i += 256) w1s[i] = w1[i];
    for (int i = tid; i < 512; i += 256) w2s[i] = w2[i];
    for (int i = tid; i < 2048; i += 256) w3s[i] = w3[i];
    if (tid < 16) { sc1s[tid] = scsh1[tid]; sh1s[tid] = scsh1[16 + tid]; }
    if (tid < 32) { sc2s[tid] = scsh2[tid]; sh2s[tid] = scsh2[32 + tid]; }
    __syncthreads();

    const float4* w1v = (const float4*)w1s;
    const float4* w2v = (const float4*)w2s;
    const float4* w3v = (const float4*)w3s;

    int lane = tid & 63;
    int pt = tid >> 4;
    int cc = tid & 15;

    float s0 = 0.f, s1 = 0.f, s2 = 0.f, s3 = 0.f;
    float q0 = 0.f, q1 = 0.f, q2 = 0.f, q3 = 0.f;

#pragma unroll 1
    for (int it = 0; it < 4; it++) {
        int r = it * 800000 + blockIdx.x * 256 + tid;
        int n = r >> 4;
        int idx = gidx[r];
        float4 fv = f[idx];
        float x[7];
        x[0] = p[idx * 3 + 0] - p[n * 3 + 0];
        x[1] = p[idx * 3 + 1] - p[n * 3 + 1];
        x[2] = p[idx * 3 + 2] - p[n * 3 + 2];
        x[3] = fv.x; x[4] = fv.y; x[5] = fv.z; x[6] = fv.w;

        float h1[16];
#pragma unroll
        for (int j0 = 0; j0 < 16; j0 += 4) {
            float y0 = 0.f, y1 = 0.f, y2 = 0.f, y3 = 0.f;
#pragma unroll
            for (int i = 0; i < 7; i++) {
                float4 w = w1v[i * 4 + (j0 >> 2)];
                float xi = x[i];
                y0 = fmaf(xi, w.x, y0); y1 = fmaf(xi, w.y, y1);
                y2 = fmaf(xi, w.z, y2); y3 = fmaf(xi, w.w, y3);
            }
            h1[j0 + 0] = gelu_f(fmaf(y0, sc1s[j0 + 0], sh1s[j0 + 0]));
            h1[j0 + 1] = gelu_f(fmaf(y1, sc1s[j0 + 1], sh1s[j0 + 1]));
            h1[j0 + 2] = gelu_f(fmaf(y2, sc1s[j0 + 2], sh1s[j0 + 2]));
            h1[j0 + 3] = gelu_f(fmaf(y3, sc1s[j0 + 3], sh1s[j0 + 3]));
        }
#pragma unroll
        for (int j0 = 0; j0 < 32; j0 += 4) {
            float y0 = 0.f, y1 = 0.f, y2 = 0.f, y3 = 0.f;
#pragma unroll
            for (int i = 0; i < 16; i++) {
                float4 w = w2v[i * 8 + (j0 >> 2)];
                float hi = h1[i];
                y0 = fmaf(hi, w.x, y0); y1 = fmaf(hi, w.y, y1);
                y2 = fmaf(hi, w.z, y2); y3 = fmaf(hi, w.w, y3);
            }
            h2t[(j0 + 0) * H2LD + tid] = gelu_f(fmaf(y0, sc2s[j0 + 0], sh2s[j0 + 0]));
            h2t[(j0 + 1) * H2LD + tid] = gelu_f(fmaf(y1, sc2s[j0 + 1], sh2s[j0 + 1]));
            h2t[(j0 + 2) * H2LD + tid] = gelu_f(fmaf(y2, sc2s[j0 + 2], sh2s[j0 + 2]));
            h2t[(j0 + 3) * H2LD + tid] = gelu_f(fmaf(y3, sc2s[j0 + 3], sh2s[j0 + 3]));
        }
        __syncthreads();

        float a[16][4];
#pragma unroll
        for (int t = 0; t < 16; t++) {
            a[t][0] = 0.f; a[t][1] = 0.f; a[t][2] = 0.f; a[t][3] = 0.f;
        }
        int rb0 = pt << 4;
#pragma unroll 8
        for (int i = 0; i < 32; i++) {
            float4 wf = w3v[i * 16 + cc];
            const float* hrow = &h2t[i * H2LD + rb0];
            float4 hA = *(const float4*)&hrow[0];
            float4 hB = *(const float4*)&hrow[4];
            float4 hC = *(const float4*)&hrow[8];
            float4 hD = *(const float4*)&hrow[12];
            float hn[16] = { hA.x, hA.y, hA.z, hA.w,
                             hB.x, hB.y, hB.z, hB.w,
                             hC.x, hC.y, hC.z, hC.w,
                             hD.x, hD.y, hD.z, hD.w };
#pragma unroll
            for (int t = 0; t < 16; t++) {
                float h = hn[t];
                a[t][0] = fmaf(h, wf.x, a[t][0]);
                a[t][1] = fmaf(h, wf.y, a[t][1]);
                a[t][2] = fmaf(h, wf.z, a[t][2]);
                a[t][3] = fmaf(h, wf.w, a[t][3]);
            }
        }
        float m0 = -3.0e38f, m1 = -3.0e38f, m2 = -3.0e38f, m3 = -3.0e38f;
#pragma unroll
        for (int t = 0; t < 16; t++) {
            m0 = fmaxf(m0, a[t][0]);
            m1 = fmaxf(m1, a[t][1]);
            m2 = fmaxf(m2, a[t][2]);
            m3 = fmaxf(m3, a[t][3]);
        }
        int np = it * 50000 + blockIdx.x * 16 + pt;
        *(float4*)&pooled[(size_t)np * 64 + cc * 4] = make_float4(m0, m1, m2, m3);
        s0 += m0; q0 = fmaf(m0, m0, q0);
        s1 += m1; q1 = fmaf(m1, m1, q1);
        s2 += m2; q2 = fmaf(m2, m2, q2);
        s3 += m3; q3 = fmaf(m3, m3, q3);
        __syncthreads();
    }

    s0 += __shfl_down(s0, 32); s0 += __shfl_down(s0, 16);
    s1 += __shfl_down(s1, 32); s1 += __shfl_down(s1, 16);
    s2 += __shfl_down(s2, 32); s2 += __shfl_down(s2, 16);
    s3 += __shfl_down(s3, 32); s3 += __shfl_down(s3, 16);
    q0 += __shfl_down(q0, 32); q0 += __shfl_down(q0, 16);
    q1 += __shfl_down(q1, 32); q1 += __shfl_down(q1, 16);
    q2 += __shfl_down(q2, 32); q2 += __shfl_down(q2, 16);
    q3 += __shfl_down(q3, 32); q3 += __shfl_down(q3, 16);
    int wv = tid >> 6;
    if (lane < 16) {
        reds[wv * 64 + lane * 4 + 0] = s0;
        reds[wv * 64 + lane * 4 + 1] = s1;
        reds[wv * 64 + lane * 4 + 2] = s2;
        reds[wv * 64 + lane * 4 + 3] = s3;
        redq[wv * 64 + lane * 4 + 0] = q0;
        redq[wv * 64 + lane * 4 + 1] = q1;
        redq[wv * 64 + lane * 4 + 2] = q2;
        redq[wv * 64 + lane * 4 + 3] = q3;
    }
    __syncthreads();
    if (tid < 64) {
        atomicAdd(&stats[tid],
                  reds[tid] + reds[64 + tid] + reds[128 + tid] + reds[192 + tid]);
        atomicAdd(&stats[64 + tid],
                  redq[tid] + redq[64 + tid] + redq[128 + tid] + redq[192 + tid]);
    }
}

// double-BN collapse
__global__ void k_fin3(const float* __restrict__ stats,
                       const float* __restrict__ g_nbr, const float* __restrict__ g_post,
                       const float* __restrict__ b_post, float* __restrict__ scsh)
{
    int j = threadIdx.x;
    if (j < 64) {
        float m = stats[j] * (1.0f / NPTS);
        float v = stats[64 + j] * (1.0f / NPTS) - m * m;
        float a1 = g_nbr[j] * rsqrtf(v + EPSB);
        float s3 = g_post[j] * a1 * rsqrtf(fmaf(a1 * a1, v, EPSB));
        scsh[j] = s3;
        scsh[64 + j] = fmaf(-m, s3, b_post[j]);
    }
}

// head: (N x 64) @ (64 x 256)
__global__ __launch_bounds__(256) void k_head(
    const float* __restrict__ pooled, const float* __restrict__ scsh3,
    const float* __restrict__ wpost, float* __restrict__ out)
{
    __shared__ float rowbuf[512];
    __shared__ float s3s[64], c3s[64];
    int tid = threadIdx.x;
    if (tid < 64) { s3s[tid] = scsh3[tid]; c3s[tid] = scsh3[64 + tid]; }
    float wcol[64];
#pragma unroll
    for (int j = 0; j < 64; j++) wcol[j] = wpost[j * 256 + tid];
    __syncthreads();

    const int nchunks = NPTS / 8;  // 25000
    for (int c = blockIdx.x; c < nchunks; c += gridDim.x) {
        int n0 = c * 8;
#pragma unroll
        for (int t = tid; t < 512; t += 256) {
            int rr = t >> 6, j = t & 63;
            rowbuf[t] = fmaf(pooled[(size_t)(n0 + rr) * 64 + j], s3s[j], c3s[j]);
        }
        __syncthreads();
#pragma unroll
        for (int rr = 0; rr < 8; rr++) {
            float acc = 0.f;
#pragma unroll
            for (int j = 0; j < 64; j++) acc = fmaf(rowbuf[rr * 64 + j], wcol[j], acc);
            out[(size_t)(n0 + rr) * 256 + tid] = acc;
        }
        __syncthreads();
    }
}

extern "C" void kernel_launch(void* const* d_in, const int* in_sizes, int n_in,
                              void* d_out, int out_size, void* d_ws, size_t ws_size,
                              hipStream_t stream)
{
    const float*  p    = (const float*)d_in[0];
    const float4* f    = (const float4*)d_in[1];
    const int*    gidx = (const int*)d_in[2];
    const float*  w1   = (const float*)d_in[3];
    const float*  g1   = (const float*)d_in[4];
    const float*  b1   = (const float*)d_in[5];
    const float*  w2   = (const float*)d_in[6];
    const float*  g2   = (const float*)d_in[7];
    const float*  b2   = (const float*)d_in[8];
    const float*  w3   = (const float*)d_in[9];
    const float*  gn   = (const float*)d_in[10];
    // d_in[11] = b_nbr: cancels exactly in the collapsed double-BN
    const float*  gp   = (const float*)d_in[12];
    const float*  bp   = (const float*)d_in[13];
    const float*  wp   = (const float*)d_in[14];
    float* out = (float*)d_out;
    float* ws  = (float*)d_ws;

    float* stats1 = ws;          // 35 floats max
    float* scsh1  = ws + 40;     // 32
    float* stats2 = ws + 80;     // 152 floats
    float* scsh2  = ws + 240;    // 64
    float* stats3 = ws + 304;    // 128
    float* scsh3  = ws + 432;    // 128
    float* pooled = ws + 1024;               // 12.8M floats (51.2 MB)
    float4* pk    = (float4*)(ws + 1024);    // aliases pooled (dead before pool writes)
    float* y1d    = ws + 1024 + 12800000;    // 51.2M floats (204.8 MB)

    const size_t need = ((size_t)1024 + 12800000 + 51200000) * 4;

    hipMemsetAsync(d_ws, 0, 2048, stream);
    k_pack<<<(NPTS + 255) / 256, 256, 0, stream>>>(p, f, pk);

    if (ws_size >= need) {
        k_gy1<<<2048, 256, 0, stream>>>(pk, gidx, w1, stats1, y1d);
        k_fin1b<<<1, 64, 0, stream>>>(stats1, g1, b1, scsh1);
        k_momA<<<2048, 256, 0, stream>>>(y1d, scsh1, stats2);
        k_momB<<<2048, 256, 0, stream>>>(y1d, scsh1, stats2);
        k_fin2<<<1, 64, 0, stream>>>(stats2, w2, g2, b2, scsh2);
        k_pool2y<<<3125, 256, 0, stream>>>(y1d, w2, w3, scsh1, scsh2, stats3, pooled);
    } else {
        k_s1g<<<2048, 256, 0, stream>>>(pk, gidx, stats1);
        k_f1g<<<1, 64, 0, stream>>>(stats1, w1, g1, b1, scsh1);
        k_s2g<0><<<2048, 256, 0, stream>>>(pk, gidx, w1, scsh1, stats2);
        k_s2g<1><<<2048, 256, 0, stream>>>(pk, gidx, w1, scsh1, stats2);
        k_fin2<<<1, 64, 0, stream>>>(stats2, w2, g2, b2, scsh2);
        k_pool2g<<<3125, 256, 0, stream>>>(p, f, gidx, w1, w2, w3, scsh1, scsh2, stats3, pooled);
    }
    k_fin3<<<1, 64, 0, stream>>>(stats3, gn, gp, bp, scsh3);
    k_head<<<1024, 256, 0, stream>>>(pooled, scsh3, wp, out);
}